// Round 11
// baseline (462.538 us; speedup 1.0000x reference)
//
#include <hip/hip_runtime.h>
#include <hip/hip_bf16.h>
#include <math.h>

// ---------------------------------------------------------------------------
// RankGNN R11: aggb/aggx restructured to 4-edges-per-gather-instruction
// (wave quarters; uint2/float loads cover 4 table rows per vmem inst);
// quarter-partial accumulators combined via shfl_xor. Rest as R10.
// ---------------------------------------------------------------------------

#define U 128
#define LDA 136    // LDS row stride in bf16 elems (128 + 8 pad)
#define WB 9       // log2(window) = 512 nodes per level-2 window
#define WSZ 512
#define NJ1 256    // level-1 blocks (edge chunks)

typedef __attribute__((ext_vector_type(8))) short bf16x8;
typedef __attribute__((ext_vector_type(4))) float f32x4;
typedef __attribute__((ext_vector_type(2))) float f32x2;

__device__ __forceinline__ unsigned short f2bf(float f) {
    unsigned u = __float_as_uint(f);
    unsigned r = (u + 0x7fffu + ((u >> 16) & 1u)) >> 16;  // RNE
    return (unsigned short)r;
}
__device__ __forceinline__ unsigned char f2fp8(float v) {
    return (unsigned char)(__builtin_amdgcn_cvt_pk_fp8_f32(v, v, 0, false) & 0xff);
}

// ---------------- level-1: per-chunk window histogram ----------------
__global__ __launch_bounds__(256) void k_hist1(const int* __restrict__ dst,
                                               int* __restrict__ hist_g, int E, int nw) {
    __shared__ int h[256];  // nw <= 256
    int b = blockIdx.x;
    for (int i = threadIdx.x; i < nw; i += 256) h[i] = 0;
    __syncthreads();
    int ch = (E + NJ1 - 1) / NJ1;
    int e0 = b * ch, e1 = min(e0 + ch, E);
    for (int e = e0 + threadIdx.x; e < e1; e += 256)
        atomicAdd(&h[dst[e] >> WB], 1);
    __syncthreads();
    for (int w = threadIdx.x; w < nw; w += 256) hist_g[w * NJ1 + b] = h[w];
}

// ---------------- generic parallel exclusive scan (in place) ----------------
__global__ __launch_bounds__(256) void k_escan1(int* __restrict__ a,
                                                int* __restrict__ bsum, int n) {
    __shared__ int sc[256];
    int t = threadIdx.x, b = blockIdx.x;
    int base = b * 1024 + t * 4;
    int v[4];
    int s = 0;
    #pragma unroll
    for (int j = 0; j < 4; ++j) {
        int idx = base + j;
        int d = (idx < n) ? a[idx] : 0;
        v[j] = s;  // exclusive within thread
        s += d;
    }
    sc[t] = s;
    __syncthreads();
    for (int off = 1; off < 256; off <<= 1) {
        int x = (t >= off) ? sc[t - off] : 0;
        __syncthreads();
        sc[t] += x;
        __syncthreads();
    }
    int excl = sc[t] - s;
    #pragma unroll
    for (int j = 0; j < 4; ++j) {
        int idx = base + j;
        if (idx < n) a[idx] = v[j] + excl;
    }
    if (t == 255) bsum[b] = sc[255];
}

__global__ __launch_bounds__(256) void k_escan2(int* __restrict__ a,
                                                const int* __restrict__ bsum,
                                                int nb, int n) {
    __shared__ int sc[256];
    int t = threadIdx.x;
    int v = (t < nb) ? bsum[t] : 0;
    sc[t] = v;
    __syncthreads();
    for (int off = 1; off < 256; off <<= 1) {
        int u = (t >= off) ? sc[t - off] : 0;
        __syncthreads();
        sc[t] += u;
        __syncthreads();
    }
    int myoff = (blockIdx.x > 0) ? (sc[blockIdx.x] - bsum[blockIdx.x]) : 0;
    int base = blockIdx.x * 1024;
    #pragma unroll
    for (int j = 0; j < 4; ++j) {
        int idx = base + t + j * 256;
        if (idx < n) a[idx] += myoff;
    }
}

// ---------------- level-1: bucket edges window-major ----------------
__global__ __launch_bounds__(256) void k_bucket(const int* __restrict__ src,
                                                const int* __restrict__ dst,
                                                const int* __restrict__ hist_g,
                                                int2* __restrict__ eb, int E, int nw) {
    __shared__ int lcur[256];
    int b = blockIdx.x;
    for (int w = threadIdx.x; w < nw; w += 256) lcur[w] = hist_g[w * NJ1 + b];
    __syncthreads();
    int ch = (E + NJ1 - 1) / NJ1;
    int e0 = b * ch, e1 = min(e0 + ch, E);
    for (int e = e0 + threadIdx.x; e < e1; e += 256) {
        int d = dst[e];
        int pos = atomicAdd(&lcur[d >> WB], 1);
        eb[pos] = make_int2(src[e], d);
    }
}

// ---------------- level-2: per-window degree histogram -> deg ---------------
__global__ __launch_bounds__(256) void k_deg2(const int2* __restrict__ eb,
                                              const int* __restrict__ hist_g,
                                              int* __restrict__ deg, int E, int nw, int N) {
    __shared__ int h[WSZ];
    int w = blockIdx.x;
    h[threadIdx.x] = 0;
    h[threadIdx.x + 256] = 0;
    __syncthreads();
    int s0 = hist_g[w * NJ1];
    int s1 = (w + 1 < nw) ? hist_g[(w + 1) * NJ1] : E;
    for (int i = s0 + threadIdx.x; i < s1; i += 256)
        atomicAdd(&h[eb[i].y & (WSZ - 1)], 1);
    __syncthreads();
    int base = w << WB;
    if (base + threadIdx.x < N) deg[base + threadIdx.x] = h[threadIdx.x];
    if (base + 256 + threadIdx.x < N) deg[base + 256 + threadIdx.x] = h[256 + threadIdx.x];
}

// ---------------- rowptr scan ----------------
__global__ __launch_bounds__(256) void k_scan1(const int* __restrict__ deg,
                                               int* __restrict__ rowptr1,
                                               int* __restrict__ bsum, int N) {
    __shared__ int sc[256];
    int t = threadIdx.x, b = blockIdx.x;
    int base = b * 1024 + t * 4;
    int v[4];
    int s = 0;
    #pragma unroll
    for (int j = 0; j < 4; ++j) {
        int idx = base + j;
        int d = (idx < N) ? deg[idx] : 0;
        s += d;
        v[j] = s;
    }
    sc[t] = s;
    __syncthreads();
    for (int off = 1; off < 256; off <<= 1) {
        int x = (t >= off) ? sc[t - off] : 0;
        __syncthreads();
        sc[t] += x;
        __syncthreads();
    }
    int excl = sc[t] - s;
    #pragma unroll
    for (int j = 0; j < 4; ++j) {
        int idx = base + j;
        if (idx < N) rowptr1[idx] = v[j] + excl;
    }
    if (t == 255) bsum[b] = sc[255];
}

__global__ __launch_bounds__(256) void k_scan23(int* __restrict__ rowptr,
                                                const int* __restrict__ bsum,
                                                int nb, int N) {
    __shared__ int sc[256];
    __shared__ int bo[256];
    int t = threadIdx.x;
    int v = (t < nb) ? bsum[t] : 0;
    sc[t] = v;
    __syncthreads();
    for (int off = 1; off < 256; off <<= 1) {
        int u = (t >= off) ? sc[t - off] : 0;
        __syncthreads();
        sc[t] += u;
        __syncthreads();
    }
    bo[t] = sc[t] - v;  // exclusive
    __syncthreads();
    int i = blockIdx.x * 256 + t;
    if (i < N) rowptr[1 + i] += bo[i >> 10];
    if (i == 0) rowptr[0] = 0;
}

// ---------------- level-2: single-writer CSR scatter ----------------
__global__ __launch_bounds__(256) void k_scatter2(const int2* __restrict__ eb,
                                                  const int* __restrict__ hist_g,
                                                  const int* __restrict__ rowptr,
                                                  int* __restrict__ csr_src,
                                                  int E, int nw, int N) {
    __shared__ int cur[WSZ];
    int w = blockIdx.x;
    int base = w << WB;
    int i0 = base + threadIdx.x, i1 = base + 256 + threadIdx.x;
    cur[threadIdx.x] = (i0 < N) ? rowptr[i0] : 0;
    cur[threadIdx.x + 256] = (i1 < N) ? rowptr[i1] : 0;
    __syncthreads();
    int s0 = hist_g[w * NJ1];
    int s1 = (w + 1 < nw) ? hist_g[(w + 1) * NJ1] : E;
    for (int i = s0 + threadIdx.x; i < s1; i += 256) {
        int2 e = eb[i];
        int pos = atomicAdd(&cur[e.y & (WSZ - 1)], 1);
        csr_src[pos] = e.x;
    }
}

// ---------------- fused prep: dinv, xs (64B rows), counts, weights ----------
__global__ __launch_bounds__(256) void k_prep(const int* __restrict__ deg,
                                              const float* __restrict__ x,
                                              const int* __restrict__ batch,
                                              const float* __restrict__ W1,
                                              const float* __restrict__ W2,
                                              const float* __restrict__ Wf1,
                                              const float* __restrict__ Wf2,
                                              float* __restrict__ dinv,
                                              float* __restrict__ xs,
                                              int* __restrict__ cnt,
                                              unsigned short* __restrict__ W1t,
                                              unsigned short* __restrict__ W2t,
                                              unsigned short* __restrict__ Wf1t,
                                              unsigned short* __restrict__ Wf2t, int N) {
    int t = blockIdx.x * 256 + threadIdx.x;
    if (t < N) {
        float dv = rsqrtf((float)deg[t] + 1.0f);
        dinv[t] = dv;
        #pragma unroll
        for (int k = 0; k < 9; ++k) xs[t * 16 + k] = x[t * 9 + k] * dv;
        #pragma unroll
        for (int k = 9; k < 16; ++k) xs[t * 16 + k] = 0.0f;
        atomicAdd(&cnt[batch[t]], 1);
    }
    if (t < 16384) {
        int n = t >> 7, k = t & 127;
        W1t[n * 128 + k] = f2bf(W1[k * 128 + n]);
        Wf1t[n * 128 + k] = f2bf(Wf1[k * 128 + n]);
    } else if (t < 32768) {
        int i = t - 16384, n = i >> 7, k = i & 127;
        W2t[n * 128 + k] = f2bf(W2[k * 128 + n]);
    } else if (t < 36864) {
        int i = t - 32768, n = i >> 7, k = i & 127;
        Wf2t[n * 128 + k] = f2bf(Wf2[k * 32 + n]);
    }
}

// ---------------- layer-1 agg: 4 edges/gather-inst (wave quarters) ----------
// xs rows are 64B (16 floats); quarter q handles edge i+q, l16 covers feats.
__global__ __launch_bounds__(256) void k_aggx(const float* __restrict__ xs,
                                              const int* __restrict__ rowptr,
                                              const int* __restrict__ csr_src,
                                              const float* __restrict__ dinv,
                                              float* __restrict__ xa, int N) {
    int node = blockIdx.x * 4 + (threadIdx.x >> 6);
    if (node >= N) return;
    int lane = threadIdx.x & 63;
    int q = lane >> 4, l16 = lane & 15;
    float a = 0.0f;
    int s = rowptr[node], e = rowptr[node + 1];
    int i = s;
    for (; i + 16 <= e; i += 16) {
        int idx[4];
        #pragma unroll
        for (int g = 0; g < 4; ++g) idx[g] = csr_src[i + g * 4 + q];
        float v[4];
        #pragma unroll
        for (int g = 0; g < 4; ++g) v[g] = xs[(size_t)idx[g] * 16 + l16];
        a += (v[0] + v[1]) + (v[2] + v[3]);
    }
    for (; i + 4 <= e; i += 4) {
        int idx = csr_src[i + q];
        a += xs[(size_t)idx * 16 + l16];
    }
    int t = e - i;
    if (t > 0) {
        int ii = i + q;
        if (ii >= e) ii = e - 1;
        float m = (q < t) ? 1.0f : 0.0f;
        a += m * xs[(size_t)csr_src[ii] * 16 + l16];
    }
    a += __shfl_xor(a, 16);
    a += __shfl_xor(a, 32);
    if (lane < 9) {
        float dv = dinv[node];
        xa[node * 9 + lane] = dv * (a + xs[node * 16 + lane]);
    }
}

// ---------------- layer-1 GEMM: bf16(tanh(xa @ W_in + b)) ----------------
__global__ void k_gemm_in9(const float* __restrict__ xa, const float* __restrict__ Wi,
                           const float* __restrict__ bi, unsigned short* __restrict__ T,
                           int N) {
    int t = blockIdx.x * 256 + threadIdx.x;
    if (t < N * U) {
        int n = t >> 7, c = t & 127;
        const float* xr = xa + n * 9;
        float acc = bi[c];
        #pragma unroll
        for (int k = 0; k < 9; ++k) acc += xr[k] * Wi[k * U + c];
        T[t] = f2bf(tanhf(acc));
    }
}

// ---------------- MFMA GEMM -> fp8 table: Ts = fp8(dinv * (A @ Wt^T)) -------
__global__ __launch_bounds__(256) void k_gemm_mfma(const unsigned short* __restrict__ A,
                                                   const unsigned short* __restrict__ Wt,
                                                   const float* __restrict__ dinv,
                                                   unsigned char* __restrict__ Out, int N) {
    const int tid = threadIdx.x;
    const int wave = tid >> 6, lane = tid & 63;
    const int m16 = lane & 15, q = lane >> 4;
    const int row0 = blockIdx.x * 64 + wave * 16;
    int arow_idx = row0 + m16;
    if (arow_idx >= N) arow_idx = N - 1;  // clamp; OOB outputs are guarded
    const bf16x8* arow = (const bf16x8*)(A + (size_t)arow_idx * U + q * 8);
    f32x4 acc[8];
    #pragma unroll
    for (int t = 0; t < 8; ++t) acc[t] = (f32x4){0.f, 0.f, 0.f, 0.f};
    #pragma unroll
    for (int kc = 0; kc < 4; ++kc) {
        bf16x8 af = arow[kc * 4];
        #pragma unroll
        for (int t = 0; t < 8; ++t) {
            bf16x8 bfr = *(const bf16x8*)(Wt + ((t * 16 + m16) * 128 + kc * 32 + q * 8));
            acc[t] = __builtin_amdgcn_mfma_f32_16x16x32_bf16(af, bfr, acc[t], 0, 0, 0);
        }
    }
    float dv[4];
    #pragma unroll
    for (int r = 0; r < 4; ++r) {
        int gr = row0 + q * 4 + r;
        dv[r] = (gr < N) ? dinv[gr] : 0.0f;
    }
    #pragma unroll
    for (int t = 0; t < 8; ++t) {
        #pragma unroll
        for (int r = 0; r < 4; ++r) {
            int gr = row0 + q * 4 + r;
            if (gr < N) Out[(size_t)gr * U + t * 16 + m16] = f2fp8(acc[t][r] * dv[r]);
        }
    }
}

// ---------------- aggregation (fp8 table): 4 edges per gather inst ----------
// Quarter q handles edge i+q; uint2/lane covers feats 8*l16..+7 of that row.
// Quarter-partials combined by shfl_xor(16/32); epilogue: 2 feats per lane.
__global__ __launch_bounds__(256) void k_aggb(const unsigned char* __restrict__ Tb,
                                              const int* __restrict__ rowptr,
                                              const int* __restrict__ csr_src,
                                              const float* __restrict__ dinv,
                                              const float* __restrict__ bias,
                                              unsigned short* __restrict__ Out, int N) {
    int node = blockIdx.x * 4 + (threadIdx.x >> 6);
    if (node >= N) return;
    int lane = threadIdx.x & 63;
    int q = lane >> 4, l16 = lane & 15;
    const uint2* T8 = (const uint2*)Tb;  // 16 uint2 per 128B row
    float a[8] = {0.f, 0.f, 0.f, 0.f, 0.f, 0.f, 0.f, 0.f};
    int s = rowptr[node], e = rowptr[node + 1];
    int i = s;
    for (; i + 16 <= e; i += 16) {
        int idx[4];
        #pragma unroll
        for (int g = 0; g < 4; ++g) idx[g] = csr_src[i + g * 4 + q];
        uint2 u[4];
        #pragma unroll
        for (int g = 0; g < 4; ++g) u[g] = T8[(size_t)idx[g] * 16 + l16];
        #pragma unroll
        for (int g = 0; g < 4; ++g) {
            f32x2 f0 = __builtin_amdgcn_cvt_pk_f32_fp8(u[g].x, false);
            f32x2 f1 = __builtin_amdgcn_cvt_pk_f32_fp8(u[g].x, true);
            f32x2 f2 = __builtin_amdgcn_cvt_pk_f32_fp8(u[g].y, false);
            f32x2 f3 = __builtin_amdgcn_cvt_pk_f32_fp8(u[g].y, true);
            a[0] += f0[0]; a[1] += f0[1]; a[2] += f1[0]; a[3] += f1[1];
            a[4] += f2[0]; a[5] += f2[1]; a[6] += f3[0]; a[7] += f3[1];
        }
    }
    for (; i + 4 <= e; i += 4) {
        int idx = csr_src[i + q];
        uint2 u = T8[(size_t)idx * 16 + l16];
        f32x2 f0 = __builtin_amdgcn_cvt_pk_f32_fp8(u.x, false);
        f32x2 f1 = __builtin_amdgcn_cvt_pk_f32_fp8(u.x, true);
        f32x2 f2 = __builtin_amdgcn_cvt_pk_f32_fp8(u.y, false);
        f32x2 f3 = __builtin_amdgcn_cvt_pk_f32_fp8(u.y, true);
        a[0] += f0[0]; a[1] += f0[1]; a[2] += f1[0]; a[3] += f1[1];
        a[4] += f2[0]; a[5] += f2[1]; a[6] += f3[0]; a[7] += f3[1];
    }
    int t = e - i;
    if (t > 0) {
        int ii = i + q;
        if (ii >= e) ii = e - 1;
        int idx = csr_src[ii];
        uint2 u = T8[(size_t)idx * 16 + l16];
        float m = (q < t) ? 1.0f : 0.0f;
        f32x2 f0 = __builtin_amdgcn_cvt_pk_f32_fp8(u.x, false);
        f32x2 f1 = __builtin_amdgcn_cvt_pk_f32_fp8(u.x, true);
        f32x2 f2 = __builtin_amdgcn_cvt_pk_f32_fp8(u.y, false);
        f32x2 f3 = __builtin_amdgcn_cvt_pk_f32_fp8(u.y, true);
        a[0] += m * f0[0]; a[1] += m * f0[1]; a[2] += m * f1[0]; a[3] += m * f1[1];
        a[4] += m * f2[0]; a[5] += m * f2[1]; a[6] += m * f3[0]; a[7] += m * f3[1];
    }
    #pragma unroll
    for (int j = 0; j < 8; ++j) {
        a[j] += __shfl_xor(a[j], 16);
        a[j] += __shfl_xor(a[j], 32);
    }
    // epilogue: this lane finishes feats f=8*l16+2q, f+1
    float sx = (q < 2) ? ((q == 0) ? a[0] : a[2]) : ((q == 2) ? a[4] : a[6]);
    float sy = (q < 2) ? ((q == 0) ? a[1] : a[3]) : ((q == 2) ? a[5] : a[7]);
    int f = 8 * l16 + 2 * q;
    float dv = dinv[node];
    unsigned short selfu = *(const unsigned short*)(Tb + (size_t)node * 128 + f);
    f32x2 fs = __builtin_amdgcn_cvt_pk_f32_fp8((unsigned)selfu, false);
    float2 bb = *(const float2*)&bias[f];
    float ox = tanhf(dv * (sx + fs[0]) + bb.x);
    float oy = tanhf(dv * (sy + fs[1]) + bb.y);
    ((unsigned*)Out)[node * 64 + (f >> 1)] = (unsigned)f2bf(ox) | ((unsigned)f2bf(oy) << 16);
}

// ---------------- fused MFMA MLP head v2 (as R9) ----------------
__global__ __launch_bounds__(256, 2) void k_mlp(const unsigned short* __restrict__ H,
                                                const unsigned short* __restrict__ Wf1t,
                                                const float* __restrict__ bf1,
                                                const unsigned short* __restrict__ Wf2t,
                                                const float* __restrict__ bf2,
                                                const float* __restrict__ Wf3,
                                                const float* __restrict__ bf3,
                                                const int* __restrict__ batch,
                                                float* __restrict__ util_sum,
                                                int N, int G) {
    __shared__ unsigned short H2[4][16 * LDA];  // per-wave transpose slice
    __shared__ float gsum[8];
    const int tid = threadIdx.x;
    if (tid < 8) gsum[tid] = 0.0f;
    const int wave = tid >> 6, lane = tid & 63;
    const int m16 = lane & 15, q = lane >> 4;
    const int blk0 = blockIdx.x * 256;
    const int g0 = batch[min(blk0, N - 1)];
    bf16x8 w1[4][8], w2[4][2];
    #pragma unroll
    for (int kc = 0; kc < 4; ++kc) {
        #pragma unroll
        for (int t = 0; t < 8; ++t)
            w1[kc][t] = *(const bf16x8*)(Wf1t + ((t * 16 + m16) * 128 + kc * 32 + q * 8));
        #pragma unroll
        for (int t = 0; t < 2; ++t)
            w2[kc][t] = *(const bf16x8*)(Wf2t + ((t * 16 + m16) * 128 + kc * 32 + q * 8));
    }
    float b1v[8];
    #pragma unroll
    for (int t = 0; t < 8; ++t) b1v[t] = bf1[t * 16 + m16];
    const float b2lo = bf2[m16], b2hi = bf2[m16 + 16];
    const float w3lo = Wf3[m16], w3hi = Wf3[m16 + 16];
    const float bf3v = bf3[0];
    __syncthreads();  // gsum init visible before tile atomics
    unsigned short* h2s = H2[wave];
    const int wbase = blk0 + wave * 64;
    bf16x8 a[4];
    {
        int ar = wbase + m16;
        if (ar >= N) ar = N - 1;
        const bf16x8* arow = (const bf16x8*)(H + (size_t)ar * U + q * 8);
        #pragma unroll
        for (int kc = 0; kc < 4; ++kc) a[kc] = arow[kc * 4];
    }
    for (int tile = 0; tile < 4; ++tile) {
        const int row0 = wbase + tile * 16;
        bf16x8 an[4];
        if (tile < 3) {
            int ar = row0 + 16 + m16;
            if (ar >= N) ar = N - 1;
            const bf16x8* arow = (const bf16x8*)(H + (size_t)ar * U + q * 8);
            #pragma unroll
            for (int kc = 0; kc < 4; ++kc) an[kc] = arow[kc * 4];
        }
        f32x4 acc[8];
        #pragma unroll
        for (int t = 0; t < 8; ++t) acc[t] = (f32x4){0.f, 0.f, 0.f, 0.f};
        #pragma unroll
        for (int kc = 0; kc < 4; ++kc) {
            #pragma unroll
            for (int t = 0; t < 8; ++t)
                acc[t] = __builtin_amdgcn_mfma_f32_16x16x32_bf16(a[kc], w1[kc][t], acc[t], 0, 0, 0);
        }
        #pragma unroll
        for (int t = 0; t < 8; ++t) {
            #pragma unroll
            for (int r = 0; r < 4; ++r) {
                int lr = q * 4 + r;
                h2s[lr * LDA + t * 16 + m16] = f2bf(tanhf(acc[t][r] + b1v[t]));
            }
        }
        f32x4 acc2[2];
        acc2[0] = (f32x4){0.f, 0.f, 0.f, 0.f};
        acc2[1] = (f32x4){0.f, 0.f, 0.f, 0.f};
        const unsigned short* h2row = h2s + m16 * LDA + q * 8;
        #pragma unroll
        for (int kc = 0; kc < 4; ++kc) {
            bf16x8 af = *(const bf16x8*)(h2row + kc * 32);
            #pragma unroll
            for (int t = 0; t < 2; ++t)
                acc2[t] = __builtin_amdgcn_mfma_f32_16x16x32_bf16(af, w2[kc][t], acc2[t], 0, 0, 0);
        }
        #pragma unroll
        for (int r = 0; r < 4; ++r) {
            float t0 = tanhf(acc2[0][r] + b2lo);
            float t1 = tanhf(acc2[1][r] + b2hi);
            float v = t0 * w3lo + t1 * w3hi;
            v += __shfl_xor(v, 1);
            v += __shfl_xor(v, 2);
            v += __shfl_xor(v, 4);
            v += __shfl_xor(v, 8);
            if (m16 == 0) {
                int n = row0 + q * 4 + r;
                if (n < N) atomicAdd(&gsum[batch[n] - g0], v + bf3v);
            }
        }
        #pragma unroll
        for (int kc = 0; kc < 4; ++kc) a[kc] = an[kc];
    }
    __syncthreads();
    if (tid < 8) {
        int g = g0 + tid;
        if (g < G) {
            float s = gsum[tid];
            if (s != 0.0f) atomicAdd(&util_sum[g], s);
        }
    }
}

// ---------------- fused output: util + pair sigmoid ----------------
__global__ void k_out(const float* __restrict__ us, const int* __restrict__ cnt,
                      const int* __restrict__ ia, const int* __restrict__ ib,
                      float* __restrict__ out, int P, int G) {
    int t = blockIdx.x * 256 + threadIdx.x;
    if (t < G) out[P + t] = us[t] / fmaxf((float)cnt[t], 1.0f);
    if (t < P) {
        int a = ia[t], b = ib[t];
        float ua = us[a] / fmaxf((float)cnt[a], 1.0f);
        float ub = us[b] / fmaxf((float)cnt[b], 1.0f);
        out[t] = 1.0f / (1.0f + expf(-(ub - ua)));
    }
}

extern "C" void kernel_launch(void* const* d_in, const int* in_sizes, int n_in,
                              void* d_out, int out_size, void* d_ws, size_t ws_size,
                              hipStream_t stream) {
    const float* x     = (const float*)d_in[0];
    const int*   eidx  = (const int*)d_in[1];
    const int*   batch = (const int*)d_in[2];
    const int*   idx_a = (const int*)d_in[3];
    const int*   idx_b = (const int*)d_in[4];
    const float* W_in  = (const float*)d_in[5];
    const float* b_in  = (const float*)d_in[6];
    const float* W1    = (const float*)d_in[7];
    const float* b1    = (const float*)d_in[8];
    const float* W2    = (const float*)d_in[9];
    const float* b2    = (const float*)d_in[10];
    const float* Wf1   = (const float*)d_in[11];
    const float* bf1   = (const float*)d_in[12];
    const float* Wf2   = (const float*)d_in[13];
    const float* bf2   = (const float*)d_in[14];
    const float* Wf3   = (const float*)d_in[15];
    const float* bf3   = (const float*)d_in[16];
    float* out = (float*)d_out;

    const int N = in_sizes[0] / 9;
    const int E = in_sizes[1] / 2;
    const int P = in_sizes[3];
    const int G = out_size - P;

    const int* src = eidx;
    const int* dst = eidx + E;

    const int nw = (N + WSZ - 1) >> WB;  // level-2 windows (196 for N=100k)
    const int nb = (N + 1023) / 1024;
    const int nh = nw * NJ1;             // hist_g size
    const int nbh = (nh + 1023) / 1024;  // scan blocks for hist_g

    // ---- workspace carve-out ----
    char* ws = (char*)d_ws;
    size_t off = 0;
    auto take = [&](size_t bytes) -> void* {
        void* p = ws + off;
        off = (off + bytes + 255) & ~(size_t)255;
        return p;
    };
    int*   deg      = (int*)  take((size_t)N * 4);
    float* dinv     = (float*)take((size_t)N * 4);
    int*   rowptr   = (int*)  take((size_t)(N + 1) * 4);
    int*   bsum     = (int*)  take(256 * 4);
    int*   bsum2    = (int*)  take(256 * 4);
    int*   hist_g   = (int*)  take((size_t)nh * 4);
    int2*  eb       = (int2*) take((size_t)E * 8);
    int*   csr_src  = (int*)  take((size_t)E * 4);
    float* xs       = (float*)take((size_t)N * 16 * 4);  // 64B-padded rows
    float* xa       = (float*)take((size_t)N * 9 * 4);
    unsigned short* bufA = (unsigned short*)take((size_t)N * U * 2);  // bf16 acts
    unsigned char*  Tb   = (unsigned char*) take((size_t)N * U);      // fp8 table
    unsigned short* W1t  = (unsigned short*)take(128 * 128 * 2);
    unsigned short* W2t  = (unsigned short*)take(128 * 128 * 2);
    unsigned short* Wf1t = (unsigned short*)take(128 * 128 * 2);
    unsigned short* Wf2t = (unsigned short*)take(32 * 128 * 2);
    // zero-region: util_sum + cnt contiguous, single memset
    float* util_sum = (float*)take((size_t)G * 4 + (size_t)G * 4);
    int*   cnt      = (int*)(util_sum + G);
    (void)ws_size;

    hipMemsetAsync(util_sum, 0, (size_t)G * 8, stream);

    // ---- CSR build: two-level counting sort ----
    k_hist1<<<NJ1, 256, 0, stream>>>(dst, hist_g, E, nw);
    k_escan1<<<nbh, 256, 0, stream>>>(hist_g, bsum2, nh);
    k_escan2<<<nbh, 256, 0, stream>>>(hist_g, bsum2, nbh, nh);
    k_bucket<<<NJ1, 256, 0, stream>>>(src, dst, hist_g, eb, E, nw);
    k_deg2<<<nw, 256, 0, stream>>>(eb, hist_g, deg, E, nw, N);
    k_prep<<<(N + 255) / 256, 256, 0, stream>>>(deg, x, batch, W1, W2, Wf1, Wf2,
                                                dinv, xs, cnt, W1t, W2t, Wf1t, Wf2t, N);
    k_scan1<<<nb, 256, 0, stream>>>(deg, rowptr + 1, bsum, N);
    k_scan23<<<(N + 255) / 256, 256, 0, stream>>>(rowptr, bsum, nb, N);
    k_scatter2<<<nw, 256, 0, stream>>>(eb, hist_g, rowptr, csr_src, E, nw, N);

    const int aggGrid  = (N + 3) / 4;
    const int gemmGrid = (N + 63) / 64;

    // ---- GCN layer 1: aggregate xs (quarter-gather), GEMM+bias+tanh -> bf16 -
    k_aggx<<<aggGrid, 256, 0, stream>>>(xs, rowptr, csr_src, dinv, xa, N);
    k_gemm_in9<<<((size_t)N * U + 255) / 256, 256, 0, stream>>>(xa, W_in, b_in, bufA, N);

    // ---- GCN layer 2 ----
    k_gemm_mfma<<<gemmGrid, 256, 0, stream>>>(bufA, W1t, dinv, Tb, N);
    k_aggb<<<aggGrid, 256, 0, stream>>>(Tb, rowptr, csr_src, dinv, b1, bufA, N);
    // ---- GCN layer 3 ----
    k_gemm_mfma<<<gemmGrid, 256, 0, stream>>>(bufA, W2t, dinv, Tb, N);
    k_aggb<<<aggGrid, 256, 0, stream>>>(Tb, rowptr, csr_src, dinv, b2, bufA, N);

    // ---- MLP head + pooled sums (256 nodes/block) ----
    k_mlp<<<(N + 255) / 256, 256, 0, stream>>>(bufA, Wf1t, bf1, Wf2t, bf2, Wf3, bf3,
                                               batch, util_sum, N, G);

    // ---- fused util + pairs ----
    int mx = (P > G ? P : G);
    k_out<<<(mx + 255) / 256, 256, 0, stream>>>(util_sum, cnt, idx_a, idx_b, out, P, G);
}

// Round 12
// 445.815 us; speedup vs baseline: 1.0375x; 1.0375x over previous
//
#include <hip/hip_runtime.h>
#include <hip/hip_bf16.h>
#include <math.h>

// ---------------------------------------------------------------------------
// RankGNN R12: revert k_aggx to R10 form (R11's wave-per-node regressed 16us);
// k_aggb keeps R11 quarter-gather + readfirstlane loop bounds + 32-bit gather
// offsets (SGPR-base addressing). Rest as R11.
// ---------------------------------------------------------------------------

#define U 128
#define LDA 136    // LDS row stride in bf16 elems (128 + 8 pad)
#define WB 9       // log2(window) = 512 nodes per level-2 window
#define WSZ 512
#define NJ1 256    // level-1 blocks (edge chunks)

typedef __attribute__((ext_vector_type(8))) short bf16x8;
typedef __attribute__((ext_vector_type(4))) float f32x4;
typedef __attribute__((ext_vector_type(2))) float f32x2;

__device__ __forceinline__ unsigned short f2bf(float f) {
    unsigned u = __float_as_uint(f);
    unsigned r = (u + 0x7fffu + ((u >> 16) & 1u)) >> 16;  // RNE
    return (unsigned short)r;
}
__device__ __forceinline__ unsigned char f2fp8(float v) {
    return (unsigned char)(__builtin_amdgcn_cvt_pk_fp8_f32(v, v, 0, false) & 0xff);
}

// ---------------- level-1: per-chunk window histogram ----------------
__global__ __launch_bounds__(256) void k_hist1(const int* __restrict__ dst,
                                               int* __restrict__ hist_g, int E, int nw) {
    __shared__ int h[256];  // nw <= 256
    int b = blockIdx.x;
    for (int i = threadIdx.x; i < nw; i += 256) h[i] = 0;
    __syncthreads();
    int ch = (E + NJ1 - 1) / NJ1;
    int e0 = b * ch, e1 = min(e0 + ch, E);
    for (int e = e0 + threadIdx.x; e < e1; e += 256)
        atomicAdd(&h[dst[e] >> WB], 1);
    __syncthreads();
    for (int w = threadIdx.x; w < nw; w += 256) hist_g[w * NJ1 + b] = h[w];
}

// ---------------- generic parallel exclusive scan (in place) ----------------
__global__ __launch_bounds__(256) void k_escan1(int* __restrict__ a,
                                                int* __restrict__ bsum, int n) {
    __shared__ int sc[256];
    int t = threadIdx.x, b = blockIdx.x;
    int base = b * 1024 + t * 4;
    int v[4];
    int s = 0;
    #pragma unroll
    for (int j = 0; j < 4; ++j) {
        int idx = base + j;
        int d = (idx < n) ? a[idx] : 0;
        v[j] = s;  // exclusive within thread
        s += d;
    }
    sc[t] = s;
    __syncthreads();
    for (int off = 1; off < 256; off <<= 1) {
        int x = (t >= off) ? sc[t - off] : 0;
        __syncthreads();
        sc[t] += x;
        __syncthreads();
    }
    int excl = sc[t] - s;
    #pragma unroll
    for (int j = 0; j < 4; ++j) {
        int idx = base + j;
        if (idx < n) a[idx] = v[j] + excl;
    }
    if (t == 255) bsum[b] = sc[255];
}

__global__ __launch_bounds__(256) void k_escan2(int* __restrict__ a,
                                                const int* __restrict__ bsum,
                                                int nb, int n) {
    __shared__ int sc[256];
    int t = threadIdx.x;
    int v = (t < nb) ? bsum[t] : 0;
    sc[t] = v;
    __syncthreads();
    for (int off = 1; off < 256; off <<= 1) {
        int u = (t >= off) ? sc[t - off] : 0;
        __syncthreads();
        sc[t] += u;
        __syncthreads();
    }
    int myoff = (blockIdx.x > 0) ? (sc[blockIdx.x] - bsum[blockIdx.x]) : 0;
    int base = blockIdx.x * 1024;
    #pragma unroll
    for (int j = 0; j < 4; ++j) {
        int idx = base + t + j * 256;
        if (idx < n) a[idx] += myoff;
    }
}

// ---------------- level-1: bucket edges window-major ----------------
__global__ __launch_bounds__(256) void k_bucket(const int* __restrict__ src,
                                                const int* __restrict__ dst,
                                                const int* __restrict__ hist_g,
                                                int2* __restrict__ eb, int E, int nw) {
    __shared__ int lcur[256];
    int b = blockIdx.x;
    for (int w = threadIdx.x; w < nw; w += 256) lcur[w] = hist_g[w * NJ1 + b];
    __syncthreads();
    int ch = (E + NJ1 - 1) / NJ1;
    int e0 = b * ch, e1 = min(e0 + ch, E);
    for (int e = e0 + threadIdx.x; e < e1; e += 256) {
        int d = dst[e];
        int pos = atomicAdd(&lcur[d >> WB], 1);
        eb[pos] = make_int2(src[e], d);
    }
}

// ---------------- level-2: per-window degree histogram -> deg ---------------
__global__ __launch_bounds__(256) void k_deg2(const int2* __restrict__ eb,
                                              const int* __restrict__ hist_g,
                                              int* __restrict__ deg, int E, int nw, int N) {
    __shared__ int h[WSZ];
    int w = blockIdx.x;
    h[threadIdx.x] = 0;
    h[threadIdx.x + 256] = 0;
    __syncthreads();
    int s0 = hist_g[w * NJ1];
    int s1 = (w + 1 < nw) ? hist_g[(w + 1) * NJ1] : E;
    for (int i = s0 + threadIdx.x; i < s1; i += 256)
        atomicAdd(&h[eb[i].y & (WSZ - 1)], 1);
    __syncthreads();
    int base = w << WB;
    if (base + threadIdx.x < N) deg[base + threadIdx.x] = h[threadIdx.x];
    if (base + 256 + threadIdx.x < N) deg[base + 256 + threadIdx.x] = h[256 + threadIdx.x];
}

// ---------------- rowptr scan ----------------
__global__ __launch_bounds__(256) void k_scan1(const int* __restrict__ deg,
                                               int* __restrict__ rowptr1,
                                               int* __restrict__ bsum, int N) {
    __shared__ int sc[256];
    int t = threadIdx.x, b = blockIdx.x;
    int base = b * 1024 + t * 4;
    int v[4];
    int s = 0;
    #pragma unroll
    for (int j = 0; j < 4; ++j) {
        int idx = base + j;
        int d = (idx < N) ? deg[idx] : 0;
        s += d;
        v[j] = s;
    }
    sc[t] = s;
    __syncthreads();
    for (int off = 1; off < 256; off <<= 1) {
        int x = (t >= off) ? sc[t - off] : 0;
        __syncthreads();
        sc[t] += x;
        __syncthreads();
    }
    int excl = sc[t] - s;
    #pragma unroll
    for (int j = 0; j < 4; ++j) {
        int idx = base + j;
        if (idx < N) rowptr1[idx] = v[j] + excl;
    }
    if (t == 255) bsum[b] = sc[255];
}

__global__ __launch_bounds__(256) void k_scan23(int* __restrict__ rowptr,
                                                const int* __restrict__ bsum,
                                                int nb, int N) {
    __shared__ int sc[256];
    __shared__ int bo[256];
    int t = threadIdx.x;
    int v = (t < nb) ? bsum[t] : 0;
    sc[t] = v;
    __syncthreads();
    for (int off = 1; off < 256; off <<= 1) {
        int u = (t >= off) ? sc[t - off] : 0;
        __syncthreads();
        sc[t] += u;
        __syncthreads();
    }
    bo[t] = sc[t] - v;  // exclusive
    __syncthreads();
    int i = blockIdx.x * 256 + t;
    if (i < N) rowptr[1 + i] += bo[i >> 10];
    if (i == 0) rowptr[0] = 0;
}

// ---------------- level-2: single-writer CSR scatter ----------------
__global__ __launch_bounds__(256) void k_scatter2(const int2* __restrict__ eb,
                                                  const int* __restrict__ hist_g,
                                                  const int* __restrict__ rowptr,
                                                  int* __restrict__ csr_src,
                                                  int E, int nw, int N) {
    __shared__ int cur[WSZ];
    int w = blockIdx.x;
    int base = w << WB;
    int i0 = base + threadIdx.x, i1 = base + 256 + threadIdx.x;
    cur[threadIdx.x] = (i0 < N) ? rowptr[i0] : 0;
    cur[threadIdx.x + 256] = (i1 < N) ? rowptr[i1] : 0;
    __syncthreads();
    int s0 = hist_g[w * NJ1];
    int s1 = (w + 1 < nw) ? hist_g[(w + 1) * NJ1] : E;
    for (int i = s0 + threadIdx.x; i < s1; i += 256) {
        int2 e = eb[i];
        int pos = atomicAdd(&cur[e.y & (WSZ - 1)], 1);
        csr_src[pos] = e.x;
    }
}

// ---------------- fused prep: dinv, xs (64B rows), counts, weights ----------
__global__ __launch_bounds__(256) void k_prep(const int* __restrict__ deg,
                                              const float* __restrict__ x,
                                              const int* __restrict__ batch,
                                              const float* __restrict__ W1,
                                              const float* __restrict__ W2,
                                              const float* __restrict__ Wf1,
                                              const float* __restrict__ Wf2,
                                              float* __restrict__ dinv,
                                              float* __restrict__ xs,
                                              int* __restrict__ cnt,
                                              unsigned short* __restrict__ W1t,
                                              unsigned short* __restrict__ W2t,
                                              unsigned short* __restrict__ Wf1t,
                                              unsigned short* __restrict__ Wf2t, int N) {
    int t = blockIdx.x * 256 + threadIdx.x;
    if (t < N) {
        float dv = rsqrtf((float)deg[t] + 1.0f);
        dinv[t] = dv;
        #pragma unroll
        for (int k = 0; k < 9; ++k) xs[t * 16 + k] = x[t * 9 + k] * dv;
        #pragma unroll
        for (int k = 9; k < 16; ++k) xs[t * 16 + k] = 0.0f;
        atomicAdd(&cnt[batch[t]], 1);
    }
    if (t < 16384) {
        int n = t >> 7, k = t & 127;
        W1t[n * 128 + k] = f2bf(W1[k * 128 + n]);
        Wf1t[n * 128 + k] = f2bf(Wf1[k * 128 + n]);
    } else if (t < 32768) {
        int i = t - 16384, n = i >> 7, k = i & 127;
        W2t[n * 128 + k] = f2bf(W2[k * 128 + n]);
    } else if (t < 36864) {
        int i = t - 32768, n = i >> 7, k = i & 127;
        Wf2t[n * 128 + k] = f2bf(Wf2[k * 32 + n]);
    }
}

// ---------------- layer-1: aggregate xs (64B rows), R10 form ----------------
__global__ __launch_bounds__(256) void k_aggx(const float* __restrict__ xs,
                                              const int* __restrict__ rowptr,
                                              const int* __restrict__ csr_src,
                                              const float* __restrict__ dinv,
                                              float* __restrict__ xa, int N) {
    int node = blockIdx.x * 16 + (threadIdx.x >> 4);
    if (node >= N) return;
    int lane = threadIdx.x & 15;
    int s = rowptr[node], e = rowptr[node + 1];
    float a0 = 0.0f, a1 = 0.0f, a2 = 0.0f, a3 = 0.0f;
    int i = s;
    for (; i + 4 <= e; i += 4) {
        int s0 = csr_src[i], s1 = csr_src[i + 1];
        int s2 = csr_src[i + 2], s3 = csr_src[i + 3];
        a0 += xs[s0 * 16 + lane];
        a1 += xs[s1 * 16 + lane];
        a2 += xs[s2 * 16 + lane];
        a3 += xs[s3 * 16 + lane];
    }
    for (; i < e; ++i) {
        int s0 = csr_src[i];
        a0 += xs[s0 * 16 + lane];
    }
    if (lane < 9) {
        float dv = dinv[node];
        xa[node * 9 + lane] = dv * (a0 + a1 + a2 + a3 + xs[node * 16 + lane]);
    }
}

// ---------------- layer-1 GEMM: bf16(tanh(xa @ W_in + b)) ----------------
__global__ void k_gemm_in9(const float* __restrict__ xa, const float* __restrict__ Wi,
                           const float* __restrict__ bi, unsigned short* __restrict__ T,
                           int N) {
    int t = blockIdx.x * 256 + threadIdx.x;
    if (t < N * U) {
        int n = t >> 7, c = t & 127;
        const float* xr = xa + n * 9;
        float acc = bi[c];
        #pragma unroll
        for (int k = 0; k < 9; ++k) acc += xr[k] * Wi[k * U + c];
        T[t] = f2bf(tanhf(acc));
    }
}

// ---------------- MFMA GEMM -> fp8 table: Ts = fp8(dinv * (A @ Wt^T)) -------
__global__ __launch_bounds__(256) void k_gemm_mfma(const unsigned short* __restrict__ A,
                                                   const unsigned short* __restrict__ Wt,
                                                   const float* __restrict__ dinv,
                                                   unsigned char* __restrict__ Out, int N) {
    const int tid = threadIdx.x;
    const int wave = tid >> 6, lane = tid & 63;
    const int m16 = lane & 15, q = lane >> 4;
    const int row0 = blockIdx.x * 64 + wave * 16;
    int arow_idx = row0 + m16;
    if (arow_idx >= N) arow_idx = N - 1;  // clamp; OOB outputs are guarded
    const bf16x8* arow = (const bf16x8*)(A + (size_t)arow_idx * U + q * 8);
    f32x4 acc[8];
    #pragma unroll
    for (int t = 0; t < 8; ++t) acc[t] = (f32x4){0.f, 0.f, 0.f, 0.f};
    #pragma unroll
    for (int kc = 0; kc < 4; ++kc) {
        bf16x8 af = arow[kc * 4];
        #pragma unroll
        for (int t = 0; t < 8; ++t) {
            bf16x8 bfr = *(const bf16x8*)(Wt + ((t * 16 + m16) * 128 + kc * 32 + q * 8));
            acc[t] = __builtin_amdgcn_mfma_f32_16x16x32_bf16(af, bfr, acc[t], 0, 0, 0);
        }
    }
    float dv[4];
    #pragma unroll
    for (int r = 0; r < 4; ++r) {
        int gr = row0 + q * 4 + r;
        dv[r] = (gr < N) ? dinv[gr] : 0.0f;
    }
    #pragma unroll
    for (int t = 0; t < 8; ++t) {
        #pragma unroll
        for (int r = 0; r < 4; ++r) {
            int gr = row0 + q * 4 + r;
            if (gr < N) Out[(size_t)gr * U + t * 16 + m16] = f2fp8(acc[t][r] * dv[r]);
        }
    }
}

// ---------------- aggregation (fp8 table): 4 edges per gather inst ----------
// Quarter q handles edge i+q; uint2/lane covers feats 8*l16..+7 of that row.
// readfirstlane loop bounds (SGPR, uniform branches); 32-bit gather offsets.
__global__ __launch_bounds__(256) void k_aggb(const unsigned char* __restrict__ Tb,
                                              const int* __restrict__ rowptr,
                                              const int* __restrict__ csr_src,
                                              const float* __restrict__ dinv,
                                              const float* __restrict__ bias,
                                              unsigned short* __restrict__ Out, int N) {
    int node = blockIdx.x * 4 + (threadIdx.x >> 6);
    if (node >= N) return;
    int lane = threadIdx.x & 63;
    int q = lane >> 4, l16 = lane & 15;
    const char* Tc = (const char*)Tb;
    const unsigned loff = (unsigned)l16 << 3;
    float a[8] = {0.f, 0.f, 0.f, 0.f, 0.f, 0.f, 0.f, 0.f};
    int s = __builtin_amdgcn_readfirstlane(rowptr[node]);
    int e = __builtin_amdgcn_readfirstlane(rowptr[node + 1]);
    int i = s;
    for (; i + 16 <= e; i += 16) {
        int idx[4];
        #pragma unroll
        for (int g = 0; g < 4; ++g) idx[g] = csr_src[i + g * 4 + q];
        uint2 u[4];
        #pragma unroll
        for (int g = 0; g < 4; ++g)
            u[g] = *(const uint2*)(Tc + (((unsigned)idx[g] << 7) + loff));
        #pragma unroll
        for (int g = 0; g < 4; ++g) {
            f32x2 f0 = __builtin_amdgcn_cvt_pk_f32_fp8(u[g].x, false);
            f32x2 f1 = __builtin_amdgcn_cvt_pk_f32_fp8(u[g].x, true);
            f32x2 f2 = __builtin_amdgcn_cvt_pk_f32_fp8(u[g].y, false);
            f32x2 f3 = __builtin_amdgcn_cvt_pk_f32_fp8(u[g].y, true);
            a[0] += f0[0]; a[1] += f0[1]; a[2] += f1[0]; a[3] += f1[1];
            a[4] += f2[0]; a[5] += f2[1]; a[6] += f3[0]; a[7] += f3[1];
        }
    }
    for (; i + 4 <= e; i += 4) {
        int idx = csr_src[i + q];
        uint2 u = *(const uint2*)(Tc + (((unsigned)idx << 7) + loff));
        f32x2 f0 = __builtin_amdgcn_cvt_pk_f32_fp8(u.x, false);
        f32x2 f1 = __builtin_amdgcn_cvt_pk_f32_fp8(u.x, true);
        f32x2 f2 = __builtin_amdgcn_cvt_pk_f32_fp8(u.y, false);
        f32x2 f3 = __builtin_amdgcn_cvt_pk_f32_fp8(u.y, true);
        a[0] += f0[0]; a[1] += f0[1]; a[2] += f1[0]; a[3] += f1[1];
        a[4] += f2[0]; a[5] += f2[1]; a[6] += f3[0]; a[7] += f3[1];
    }
    int t = e - i;
    if (t > 0) {
        int ii = i + q;
        if (ii >= e) ii = e - 1;
        int idx = csr_src[ii];
        uint2 u = *(const uint2*)(Tc + (((unsigned)idx << 7) + loff));
        float m = (q < t) ? 1.0f : 0.0f;
        f32x2 f0 = __builtin_amdgcn_cvt_pk_f32_fp8(u.x, false);
        f32x2 f1 = __builtin_amdgcn_cvt_pk_f32_fp8(u.x, true);
        f32x2 f2 = __builtin_amdgcn_cvt_pk_f32_fp8(u.y, false);
        f32x2 f3 = __builtin_amdgcn_cvt_pk_f32_fp8(u.y, true);
        a[0] += m * f0[0]; a[1] += m * f0[1]; a[2] += m * f1[0]; a[3] += m * f1[1];
        a[4] += m * f2[0]; a[5] += m * f2[1]; a[6] += m * f3[0]; a[7] += m * f3[1];
    }
    #pragma unroll
    for (int j = 0; j < 8; ++j) {
        a[j] += __shfl_xor(a[j], 16);
        a[j] += __shfl_xor(a[j], 32);
    }
    // epilogue: this lane finishes feats f=8*l16+2q, f+1
    float sx = (q < 2) ? ((q == 0) ? a[0] : a[2]) : ((q == 2) ? a[4] : a[6]);
    float sy = (q < 2) ? ((q == 0) ? a[1] : a[3]) : ((q == 2) ? a[5] : a[7]);
    int f = 8 * l16 + 2 * q;
    float dv = dinv[node];
    unsigned short selfu = *(const unsigned short*)(Tc + ((unsigned)node << 7) + f);
    f32x2 fs = __builtin_amdgcn_cvt_pk_f32_fp8((unsigned)selfu, false);
    float2 bb = *(const float2*)&bias[f];
    float ox = tanhf(dv * (sx + fs[0]) + bb.x);
    float oy = tanhf(dv * (sy + fs[1]) + bb.y);
    ((unsigned*)Out)[node * 64 + (f >> 1)] = (unsigned)f2bf(ox) | ((unsigned)f2bf(oy) << 16);
}

// ---------------- fused MFMA MLP head v2 (as R9) ----------------
__global__ __launch_bounds__(256, 2) void k_mlp(const unsigned short* __restrict__ H,
                                                const unsigned short* __restrict__ Wf1t,
                                                const float* __restrict__ bf1,
                                                const unsigned short* __restrict__ Wf2t,
                                                const float* __restrict__ bf2,
                                                const float* __restrict__ Wf3,
                                                const float* __restrict__ bf3,
                                                const int* __restrict__ batch,
                                                float* __restrict__ util_sum,
                                                int N, int G) {
    __shared__ unsigned short H2[4][16 * LDA];  // per-wave transpose slice
    __shared__ float gsum[8];
    const int tid = threadIdx.x;
    if (tid < 8) gsum[tid] = 0.0f;
    const int wave = tid >> 6, lane = tid & 63;
    const int m16 = lane & 15, q = lane >> 4;
    const int blk0 = blockIdx.x * 256;
    const int g0 = batch[min(blk0, N - 1)];
    bf16x8 w1[4][8], w2[4][2];
    #pragma unroll
    for (int kc = 0; kc < 4; ++kc) {
        #pragma unroll
        for (int t = 0; t < 8; ++t)
            w1[kc][t] = *(const bf16x8*)(Wf1t + ((t * 16 + m16) * 128 + kc * 32 + q * 8));
        #pragma unroll
        for (int t = 0; t < 2; ++t)
            w2[kc][t] = *(const bf16x8*)(Wf2t + ((t * 16 + m16) * 128 + kc * 32 + q * 8));
    }
    float b1v[8];
    #pragma unroll
    for (int t = 0; t < 8; ++t) b1v[t] = bf1[t * 16 + m16];
    const float b2lo = bf2[m16], b2hi = bf2[m16 + 16];
    const float w3lo = Wf3[m16], w3hi = Wf3[m16 + 16];
    const float bf3v = bf3[0];
    __syncthreads();  // gsum init visible before tile atomics
    unsigned short* h2s = H2[wave];
    const int wbase = blk0 + wave * 64;
    bf16x8 a[4];
    {
        int ar = wbase + m16;
        if (ar >= N) ar = N - 1;
        const bf16x8* arow = (const bf16x8*)(H + (size_t)ar * U + q * 8);
        #pragma unroll
        for (int kc = 0; kc < 4; ++kc) a[kc] = arow[kc * 4];
    }
    for (int tile = 0; tile < 4; ++tile) {
        const int row0 = wbase + tile * 16;
        bf16x8 an[4];
        if (tile < 3) {
            int ar = row0 + 16 + m16;
            if (ar >= N) ar = N - 1;
            const bf16x8* arow = (const bf16x8*)(H + (size_t)ar * U + q * 8);
            #pragma unroll
            for (int kc = 0; kc < 4; ++kc) an[kc] = arow[kc * 4];
        }
        f32x4 acc[8];
        #pragma unroll
        for (int t = 0; t < 8; ++t) acc[t] = (f32x4){0.f, 0.f, 0.f, 0.f};
        #pragma unroll
        for (int kc = 0; kc < 4; ++kc) {
            #pragma unroll
            for (int t = 0; t < 8; ++t)
                acc[t] = __builtin_amdgcn_mfma_f32_16x16x32_bf16(a[kc], w1[kc][t], acc[t], 0, 0, 0);
        }
        #pragma unroll
        for (int t = 0; t < 8; ++t) {
            #pragma unroll
            for (int r = 0; r < 4; ++r) {
                int lr = q * 4 + r;
                h2s[lr * LDA + t * 16 + m16] = f2bf(tanhf(acc[t][r] + b1v[t]));
            }
        }
        f32x4 acc2[2];
        acc2[0] = (f32x4){0.f, 0.f, 0.f, 0.f};
        acc2[1] = (f32x4){0.f, 0.f, 0.f, 0.f};
        const unsigned short* h2row = h2s + m16 * LDA + q * 8;
        #pragma unroll
        for (int kc = 0; kc < 4; ++kc) {
            bf16x8 af = *(const bf16x8*)(h2row + kc * 32);
            #pragma unroll
            for (int t = 0; t < 2; ++t)
                acc2[t] = __builtin_amdgcn_mfma_f32_16x16x32_bf16(af, w2[kc][t], acc2[t], 0, 0, 0);
        }
        #pragma unroll
        for (int r = 0; r < 4; ++r) {
            float t0 = tanhf(acc2[0][r] + b2lo);
            float t1 = tanhf(acc2[1][r] + b2hi);
            float v = t0 * w3lo + t1 * w3hi;
            v += __shfl_xor(v, 1);
            v += __shfl_xor(v, 2);
            v += __shfl_xor(v, 4);
            v += __shfl_xor(v, 8);
            if (m16 == 0) {
                int n = row0 + q * 4 + r;
                if (n < N) atomicAdd(&gsum[batch[n] - g0], v + bf3v);
            }
        }
        #pragma unroll
        for (int kc = 0; kc < 4; ++kc) a[kc] = an[kc];
    }
    __syncthreads();
    if (tid < 8) {
        int g = g0 + tid;
        if (g < G) {
            float s = gsum[tid];
            if (s != 0.0f) atomicAdd(&util_sum[g], s);
        }
    }
}

// ---------------- fused output: util + pair sigmoid ----------------
__global__ void k_out(const float* __restrict__ us, const int* __restrict__ cnt,
                      const int* __restrict__ ia, const int* __restrict__ ib,
                      float* __restrict__ out, int P, int G) {
    int t = blockIdx.x * 256 + threadIdx.x;
    if (t < G) out[P + t] = us[t] / fmaxf((float)cnt[t], 1.0f);
    if (t < P) {
        int a = ia[t], b = ib[t];
        float ua = us[a] / fmaxf((float)cnt[a], 1.0f);
        float ub = us[b] / fmaxf((float)cnt[b], 1.0f);
        out[t] = 1.0f / (1.0f + expf(-(ub - ua)));
    }
}

extern "C" void kernel_launch(void* const* d_in, const int* in_sizes, int n_in,
                              void* d_out, int out_size, void* d_ws, size_t ws_size,
                              hipStream_t stream) {
    const float* x     = (const float*)d_in[0];
    const int*   eidx  = (const int*)d_in[1];
    const int*   batch = (const int*)d_in[2];
    const int*   idx_a = (const int*)d_in[3];
    const int*   idx_b = (const int*)d_in[4];
    const float* W_in  = (const float*)d_in[5];
    const float* b_in  = (const float*)d_in[6];
    const float* W1    = (const float*)d_in[7];
    const float* b1    = (const float*)d_in[8];
    const float* W2    = (const float*)d_in[9];
    const float* b2    = (const float*)d_in[10];
    const float* Wf1   = (const float*)d_in[11];
    const float* bf1   = (const float*)d_in[12];
    const float* Wf2   = (const float*)d_in[13];
    const float* bf2   = (const float*)d_in[14];
    const float* Wf3   = (const float*)d_in[15];
    const float* bf3   = (const float*)d_in[16];
    float* out = (float*)d_out;

    const int N = in_sizes[0] / 9;
    const int E = in_sizes[1] / 2;
    const int P = in_sizes[3];
    const int G = out_size - P;

    const int* src = eidx;
    const int* dst = eidx + E;

    const int nw = (N + WSZ - 1) >> WB;  // level-2 windows (196 for N=100k)
    const int nb = (N + 1023) / 1024;
    const int nh = nw * NJ1;             // hist_g size
    const int nbh = (nh + 1023) / 1024;  // scan blocks for hist_g

    // ---- workspace carve-out ----
    char* ws = (char*)d_ws;
    size_t off = 0;
    auto take = [&](size_t bytes) -> void* {
        void* p = ws + off;
        off = (off + bytes + 255) & ~(size_t)255;
        return p;
    };
    int*   deg      = (int*)  take((size_t)N * 4);
    float* dinv     = (float*)take((size_t)N * 4);
    int*   rowptr   = (int*)  take((size_t)(N + 1) * 4);
    int*   bsum     = (int*)  take(256 * 4);
    int*   bsum2    = (int*)  take(256 * 4);
    int*   hist_g   = (int*)  take((size_t)nh * 4);
    int2*  eb       = (int2*) take((size_t)E * 8);
    int*   csr_src  = (int*)  take((size_t)E * 4);
    float* xs       = (float*)take((size_t)N * 16 * 4);  // 64B-padded rows
    float* xa       = (float*)take((size_t)N * 9 * 4);
    unsigned short* bufA = (unsigned short*)take((size_t)N * U * 2);  // bf16 acts
    unsigned char*  Tb   = (unsigned char*) take((size_t)N * U);      // fp8 table
    unsigned short* W1t  = (unsigned short*)take(128 * 128 * 2);
    unsigned short* W2t  = (unsigned short*)take(128 * 128 * 2);
    unsigned short* Wf1t = (unsigned short*)take(128 * 128 * 2);
    unsigned short* Wf2t = (unsigned short*)take(32 * 128 * 2);
    // zero-region: util_sum + cnt contiguous, single memset
    float* util_sum = (float*)take((size_t)G * 4 + (size_t)G * 4);
    int*   cnt      = (int*)(util_sum + G);
    (void)ws_size;

    hipMemsetAsync(util_sum, 0, (size_t)G * 8, stream);

    // ---- CSR build: two-level counting sort ----
    k_hist1<<<NJ1, 256, 0, stream>>>(dst, hist_g, E, nw);
    k_escan1<<<nbh, 256, 0, stream>>>(hist_g, bsum2, nh);
    k_escan2<<<nbh, 256, 0, stream>>>(hist_g, bsum2, nbh, nh);
    k_bucket<<<NJ1, 256, 0, stream>>>(src, dst, hist_g, eb, E, nw);
    k_deg2<<<nw, 256, 0, stream>>>(eb, hist_g, deg, E, nw, N);
    k_prep<<<(N + 255) / 256, 256, 0, stream>>>(deg, x, batch, W1, W2, Wf1, Wf2,
                                                dinv, xs, cnt, W1t, W2t, Wf1t, Wf2t, N);
    k_scan1<<<nb, 256, 0, stream>>>(deg, rowptr + 1, bsum, N);
    k_scan23<<<(N + 255) / 256, 256, 0, stream>>>(rowptr, bsum, nb, N);
    k_scatter2<<<nw, 256, 0, stream>>>(eb, hist_g, rowptr, csr_src, E, nw, N);

    const int aggGrid  = (N + 3) / 4;
    const int gemmGrid = (N + 63) / 64;

    // ---- GCN layer 1: aggregate xs (R10 form), GEMM+bias+tanh -> bf16 ----
    k_aggx<<<(N + 15) / 16, 256, 0, stream>>>(xs, rowptr, csr_src, dinv, xa, N);
    k_gemm_in9<<<((size_t)N * U + 255) / 256, 256, 0, stream>>>(xa, W_in, b_in, bufA, N);

    // ---- GCN layer 2 ----
    k_gemm_mfma<<<gemmGrid, 256, 0, stream>>>(bufA, W1t, dinv, Tb, N);
    k_aggb<<<aggGrid, 256, 0, stream>>>(Tb, rowptr, csr_src, dinv, b1, bufA, N);
    // ---- GCN layer 3 ----
    k_gemm_mfma<<<gemmGrid, 256, 0, stream>>>(bufA, W2t, dinv, Tb, N);
    k_aggb<<<aggGrid, 256, 0, stream>>>(Tb, rowptr, csr_src, dinv, b2, bufA, N);

    // ---- MLP head + pooled sums (256 nodes/block) ----
    k_mlp<<<(N + 255) / 256, 256, 0, stream>>>(bufA, Wf1t, bf1, Wf2t, bf2, Wf3, bf3,
                                               batch, util_sum, N, G);

    // ---- fused util + pairs ----
    int mx = (P > G ? P : G);
    k_out<<<(mx + 255) / 256, 256, 0, stream>>>(util_sum, cnt, idx_a, idx_b, out, P, G);
}

// Round 13
// 437.224 us; speedup vs baseline: 1.0579x; 1.0196x over previous
//
#include <hip/hip_runtime.h>
#include <hip/hip_bf16.h>
#include <math.h>

// ---------------------------------------------------------------------------
// RankGNN R13: k_aggb processes 2 nodes per wave (software-interleaved edge
// streams -> 2x outstanding gathers; latency-bound kernel). Rest as R12.
// ---------------------------------------------------------------------------

#define U 128
#define LDA 136    // LDS row stride in bf16 elems (128 + 8 pad)
#define WB 9       // log2(window) = 512 nodes per level-2 window
#define WSZ 512
#define NJ1 256    // level-1 blocks (edge chunks)

typedef __attribute__((ext_vector_type(8))) short bf16x8;
typedef __attribute__((ext_vector_type(4))) float f32x4;
typedef __attribute__((ext_vector_type(2))) float f32x2;

__device__ __forceinline__ unsigned short f2bf(float f) {
    unsigned u = __float_as_uint(f);
    unsigned r = (u + 0x7fffu + ((u >> 16) & 1u)) >> 16;  // RNE
    return (unsigned short)r;
}
__device__ __forceinline__ unsigned char f2fp8(float v) {
    return (unsigned char)(__builtin_amdgcn_cvt_pk_fp8_f32(v, v, 0, false) & 0xff);
}
__device__ __forceinline__ void acc8(float* a, uint2 u) {
    f32x2 f0 = __builtin_amdgcn_cvt_pk_f32_fp8(u.x, false);
    f32x2 f1 = __builtin_amdgcn_cvt_pk_f32_fp8(u.x, true);
    f32x2 f2 = __builtin_amdgcn_cvt_pk_f32_fp8(u.y, false);
    f32x2 f3 = __builtin_amdgcn_cvt_pk_f32_fp8(u.y, true);
    a[0] += f0[0]; a[1] += f0[1]; a[2] += f1[0]; a[3] += f1[1];
    a[4] += f2[0]; a[5] += f2[1]; a[6] += f3[0]; a[7] += f3[1];
}
__device__ __forceinline__ void acc8m(float* a, uint2 u, float m) {
    f32x2 f0 = __builtin_amdgcn_cvt_pk_f32_fp8(u.x, false);
    f32x2 f1 = __builtin_amdgcn_cvt_pk_f32_fp8(u.x, true);
    f32x2 f2 = __builtin_amdgcn_cvt_pk_f32_fp8(u.y, false);
    f32x2 f3 = __builtin_amdgcn_cvt_pk_f32_fp8(u.y, true);
    a[0] += m * f0[0]; a[1] += m * f0[1]; a[2] += m * f1[0]; a[3] += m * f1[1];
    a[4] += m * f2[0]; a[5] += m * f2[1]; a[6] += m * f3[0]; a[7] += m * f3[1];
}

// ---------------- level-1: per-chunk window histogram ----------------
__global__ __launch_bounds__(256) void k_hist1(const int* __restrict__ dst,
                                               int* __restrict__ hist_g, int E, int nw) {
    __shared__ int h[256];  // nw <= 256
    int b = blockIdx.x;
    for (int i = threadIdx.x; i < nw; i += 256) h[i] = 0;
    __syncthreads();
    int ch = (E + NJ1 - 1) / NJ1;
    int e0 = b * ch, e1 = min(e0 + ch, E);
    for (int e = e0 + threadIdx.x; e < e1; e += 256)
        atomicAdd(&h[dst[e] >> WB], 1);
    __syncthreads();
    for (int w = threadIdx.x; w < nw; w += 256) hist_g[w * NJ1 + b] = h[w];
}

// ---------------- generic parallel exclusive scan (in place) ----------------
__global__ __launch_bounds__(256) void k_escan1(int* __restrict__ a,
                                                int* __restrict__ bsum, int n) {
    __shared__ int sc[256];
    int t = threadIdx.x, b = blockIdx.x;
    int base = b * 1024 + t * 4;
    int v[4];
    int s = 0;
    #pragma unroll
    for (int j = 0; j < 4; ++j) {
        int idx = base + j;
        int d = (idx < n) ? a[idx] : 0;
        v[j] = s;  // exclusive within thread
        s += d;
    }
    sc[t] = s;
    __syncthreads();
    for (int off = 1; off < 256; off <<= 1) {
        int x = (t >= off) ? sc[t - off] : 0;
        __syncthreads();
        sc[t] += x;
        __syncthreads();
    }
    int excl = sc[t] - s;
    #pragma unroll
    for (int j = 0; j < 4; ++j) {
        int idx = base + j;
        if (idx < n) a[idx] = v[j] + excl;
    }
    if (t == 255) bsum[b] = sc[255];
}

__global__ __launch_bounds__(256) void k_escan2(int* __restrict__ a,
                                                const int* __restrict__ bsum,
                                                int nb, int n) {
    __shared__ int sc[256];
    int t = threadIdx.x;
    int v = (t < nb) ? bsum[t] : 0;
    sc[t] = v;
    __syncthreads();
    for (int off = 1; off < 256; off <<= 1) {
        int u = (t >= off) ? sc[t - off] : 0;
        __syncthreads();
        sc[t] += u;
        __syncthreads();
    }
    int myoff = (blockIdx.x > 0) ? (sc[blockIdx.x] - bsum[blockIdx.x]) : 0;
    int base = blockIdx.x * 1024;
    #pragma unroll
    for (int j = 0; j < 4; ++j) {
        int idx = base + t + j * 256;
        if (idx < n) a[idx] += myoff;
    }
}

// ---------------- level-1: bucket edges window-major ----------------
__global__ __launch_bounds__(256) void k_bucket(const int* __restrict__ src,
                                                const int* __restrict__ dst,
                                                const int* __restrict__ hist_g,
                                                int2* __restrict__ eb, int E, int nw) {
    __shared__ int lcur[256];
    int b = blockIdx.x;
    for (int w = threadIdx.x; w < nw; w += 256) lcur[w] = hist_g[w * NJ1 + b];
    __syncthreads();
    int ch = (E + NJ1 - 1) / NJ1;
    int e0 = b * ch, e1 = min(e0 + ch, E);
    for (int e = e0 + threadIdx.x; e < e1; e += 256) {
        int d = dst[e];
        int pos = atomicAdd(&lcur[d >> WB], 1);
        eb[pos] = make_int2(src[e], d);
    }
}

// ---------------- level-2: per-window degree histogram -> deg ---------------
__global__ __launch_bounds__(256) void k_deg2(const int2* __restrict__ eb,
                                              const int* __restrict__ hist_g,
                                              int* __restrict__ deg, int E, int nw, int N) {
    __shared__ int h[WSZ];
    int w = blockIdx.x;
    h[threadIdx.x] = 0;
    h[threadIdx.x + 256] = 0;
    __syncthreads();
    int s0 = hist_g[w * NJ1];
    int s1 = (w + 1 < nw) ? hist_g[(w + 1) * NJ1] : E;
    for (int i = s0 + threadIdx.x; i < s1; i += 256)
        atomicAdd(&h[eb[i].y & (WSZ - 1)], 1);
    __syncthreads();
    int base = w << WB;
    if (base + threadIdx.x < N) deg[base + threadIdx.x] = h[threadIdx.x];
    if (base + 256 + threadIdx.x < N) deg[base + 256 + threadIdx.x] = h[256 + threadIdx.x];
}

// ---------------- rowptr scan ----------------
__global__ __launch_bounds__(256) void k_scan1(const int* __restrict__ deg,
                                               int* __restrict__ rowptr1,
                                               int* __restrict__ bsum, int N) {
    __shared__ int sc[256];
    int t = threadIdx.x, b = blockIdx.x;
    int base = b * 1024 + t * 4;
    int v[4];
    int s = 0;
    #pragma unroll
    for (int j = 0; j < 4; ++j) {
        int idx = base + j;
        int d = (idx < N) ? deg[idx] : 0;
        s += d;
        v[j] = s;
    }
    sc[t] = s;
    __syncthreads();
    for (int off = 1; off < 256; off <<= 1) {
        int x = (t >= off) ? sc[t - off] : 0;
        __syncthreads();
        sc[t] += x;
        __syncthreads();
    }
    int excl = sc[t] - s;
    #pragma unroll
    for (int j = 0; j < 4; ++j) {
        int idx = base + j;
        if (idx < N) rowptr1[idx] = v[j] + excl;
    }
    if (t == 255) bsum[b] = sc[255];
}

__global__ __launch_bounds__(256) void k_scan23(int* __restrict__ rowptr,
                                                const int* __restrict__ bsum,
                                                int nb, int N) {
    __shared__ int sc[256];
    __shared__ int bo[256];
    int t = threadIdx.x;
    int v = (t < nb) ? bsum[t] : 0;
    sc[t] = v;
    __syncthreads();
    for (int off = 1; off < 256; off <<= 1) {
        int u = (t >= off) ? sc[t - off] : 0;
        __syncthreads();
        sc[t] += u;
        __syncthreads();
    }
    bo[t] = sc[t] - v;  // exclusive
    __syncthreads();
    int i = blockIdx.x * 256 + t;
    if (i < N) rowptr[1 + i] += bo[i >> 10];
    if (i == 0) rowptr[0] = 0;
}

// ---------------- level-2: single-writer CSR scatter ----------------
__global__ __launch_bounds__(256) void k_scatter2(const int2* __restrict__ eb,
                                                  const int* __restrict__ hist_g,
                                                  const int* __restrict__ rowptr,
                                                  int* __restrict__ csr_src,
                                                  int E, int nw, int N) {
    __shared__ int cur[WSZ];
    int w = blockIdx.x;
    int base = w << WB;
    int i0 = base + threadIdx.x, i1 = base + 256 + threadIdx.x;
    cur[threadIdx.x] = (i0 < N) ? rowptr[i0] : 0;
    cur[threadIdx.x + 256] = (i1 < N) ? rowptr[i1] : 0;
    __syncthreads();
    int s0 = hist_g[w * NJ1];
    int s1 = (w + 1 < nw) ? hist_g[(w + 1) * NJ1] : E;
    for (int i = s0 + threadIdx.x; i < s1; i += 256) {
        int2 e = eb[i];
        int pos = atomicAdd(&cur[e.y & (WSZ - 1)], 1);
        csr_src[pos] = e.x;
    }
}

// ---------------- fused prep: dinv, xs (64B rows), counts, weights ----------
__global__ __launch_bounds__(256) void k_prep(const int* __restrict__ deg,
                                              const float* __restrict__ x,
                                              const int* __restrict__ batch,
                                              const float* __restrict__ W1,
                                              const float* __restrict__ W2,
                                              const float* __restrict__ Wf1,
                                              const float* __restrict__ Wf2,
                                              float* __restrict__ dinv,
                                              float* __restrict__ xs,
                                              int* __restrict__ cnt,
                                              unsigned short* __restrict__ W1t,
                                              unsigned short* __restrict__ W2t,
                                              unsigned short* __restrict__ Wf1t,
                                              unsigned short* __restrict__ Wf2t, int N) {
    int t = blockIdx.x * 256 + threadIdx.x;
    if (t < N) {
        float dv = rsqrtf((float)deg[t] + 1.0f);
        dinv[t] = dv;
        #pragma unroll
        for (int k = 0; k < 9; ++k) xs[t * 16 + k] = x[t * 9 + k] * dv;
        #pragma unroll
        for (int k = 9; k < 16; ++k) xs[t * 16 + k] = 0.0f;
        atomicAdd(&cnt[batch[t]], 1);
    }
    if (t < 16384) {
        int n = t >> 7, k = t & 127;
        W1t[n * 128 + k] = f2bf(W1[k * 128 + n]);
        Wf1t[n * 128 + k] = f2bf(Wf1[k * 128 + n]);
    } else if (t < 32768) {
        int i = t - 16384, n = i >> 7, k = i & 127;
        W2t[n * 128 + k] = f2bf(W2[k * 128 + n]);
    } else if (t < 36864) {
        int i = t - 32768, n = i >> 7, k = i & 127;
        Wf2t[n * 128 + k] = f2bf(Wf2[k * 32 + n]);
    }
}

// ---------------- layer-1: aggregate xs (64B rows), R10 form ----------------
__global__ __launch_bounds__(256) void k_aggx(const float* __restrict__ xs,
                                              const int* __restrict__ rowptr,
                                              const int* __restrict__ csr_src,
                                              const float* __restrict__ dinv,
                                              float* __restrict__ xa, int N) {
    int node = blockIdx.x * 16 + (threadIdx.x >> 4);
    if (node >= N) return;
    int lane = threadIdx.x & 15;
    int s = rowptr[node], e = rowptr[node + 1];
    float a0 = 0.0f, a1 = 0.0f, a2 = 0.0f, a3 = 0.0f;
    int i = s;
    for (; i + 4 <= e; i += 4) {
        int s0 = csr_src[i], s1 = csr_src[i + 1];
        int s2 = csr_src[i + 2], s3 = csr_src[i + 3];
        a0 += xs[s0 * 16 + lane];
        a1 += xs[s1 * 16 + lane];
        a2 += xs[s2 * 16 + lane];
        a3 += xs[s3 * 16 + lane];
    }
    for (; i < e; ++i) {
        int s0 = csr_src[i];
        a0 += xs[s0 * 16 + lane];
    }
    if (lane < 9) {
        float dv = dinv[node];
        xa[node * 9 + lane] = dv * (a0 + a1 + a2 + a3 + xs[node * 16 + lane]);
    }
}

// ---------------- layer-1 GEMM: bf16(tanh(xa @ W_in + b)) ----------------
__global__ void k_gemm_in9(const float* __restrict__ xa, const float* __restrict__ Wi,
                           const float* __restrict__ bi, unsigned short* __restrict__ T,
                           int N) {
    int t = blockIdx.x * 256 + threadIdx.x;
    if (t < N * U) {
        int n = t >> 7, c = t & 127;
        const float* xr = xa + n * 9;
        float acc = bi[c];
        #pragma unroll
        for (int k = 0; k < 9; ++k) acc += xr[k] * Wi[k * U + c];
        T[t] = f2bf(tanhf(acc));
    }
}

// ---------------- MFMA GEMM -> fp8 table: Ts = fp8(dinv * (A @ Wt^T)) -------
__global__ __launch_bounds__(256) void k_gemm_mfma(const unsigned short* __restrict__ A,
                                                   const unsigned short* __restrict__ Wt,
                                                   const float* __restrict__ dinv,
                                                   unsigned char* __restrict__ Out, int N) {
    const int tid = threadIdx.x;
    const int wave = tid >> 6, lane = tid & 63;
    const int m16 = lane & 15, q = lane >> 4;
    const int row0 = blockIdx.x * 64 + wave * 16;
    int arow_idx = row0 + m16;
    if (arow_idx >= N) arow_idx = N - 1;  // clamp; OOB outputs are guarded
    const bf16x8* arow = (const bf16x8*)(A + (size_t)arow_idx * U + q * 8);
    f32x4 acc[8];
    #pragma unroll
    for (int t = 0; t < 8; ++t) acc[t] = (f32x4){0.f, 0.f, 0.f, 0.f};
    #pragma unroll
    for (int kc = 0; kc < 4; ++kc) {
        bf16x8 af = arow[kc * 4];
        #pragma unroll
        for (int t = 0; t < 8; ++t) {
            bf16x8 bfr = *(const bf16x8*)(Wt + ((t * 16 + m16) * 128 + kc * 32 + q * 8));
            acc[t] = __builtin_amdgcn_mfma_f32_16x16x32_bf16(af, bfr, acc[t], 0, 0, 0);
        }
    }
    float dv[4];
    #pragma unroll
    for (int r = 0; r < 4; ++r) {
        int gr = row0 + q * 4 + r;
        dv[r] = (gr < N) ? dinv[gr] : 0.0f;
    }
    #pragma unroll
    for (int t = 0; t < 8; ++t) {
        #pragma unroll
        for (int r = 0; r < 4; ++r) {
            int gr = row0 + q * 4 + r;
            if (gr < N) Out[(size_t)gr * U + t * 16 + m16] = f2fp8(acc[t][r] * dv[r]);
        }
    }
}

// ---------------- aggregation (fp8 table): 2 nodes/wave, 4 edges/gather -----
__global__ __launch_bounds__(256) void k_aggb(const unsigned char* __restrict__ Tb,
                                              const int* __restrict__ rowptr,
                                              const int* __restrict__ csr_src,
                                              const float* __restrict__ dinv,
                                              const float* __restrict__ bias,
                                              unsigned short* __restrict__ Out, int N) {
    int n0 = blockIdx.x * 8 + ((threadIdx.x >> 6) << 1);
    if (n0 >= N) return;
    int n1 = n0 + 1;
    bool has1 = (n1 < N);
    if (!has1) n1 = n0;
    int lane = threadIdx.x & 63;
    int q = lane >> 4, l16 = lane & 15;
    const char* Tc = (const char*)Tb;
    const unsigned loff = (unsigned)l16 << 3;
    float a0[8] = {0.f, 0.f, 0.f, 0.f, 0.f, 0.f, 0.f, 0.f};
    float a1[8] = {0.f, 0.f, 0.f, 0.f, 0.f, 0.f, 0.f, 0.f};
    int s0 = __builtin_amdgcn_readfirstlane(rowptr[n0]);
    int e0 = __builtin_amdgcn_readfirstlane(rowptr[n0 + 1]);
    int s1 = __builtin_amdgcn_readfirstlane(rowptr[n1]);
    int e1 = __builtin_amdgcn_readfirstlane(rowptr[n1 + 1]);
    int i0 = s0, i1 = s1;
    // ---- joint 16+16: 8 gathers in flight ----
    while (i0 + 16 <= e0 && i1 + 16 <= e1) {
        int iA[4], iB[4];
        #pragma unroll
        for (int g = 0; g < 4; ++g) {
            iA[g] = csr_src[i0 + g * 4 + q];
            iB[g] = csr_src[i1 + g * 4 + q];
        }
        uint2 uA[4], uB[4];
        #pragma unroll
        for (int g = 0; g < 4; ++g) {
            uA[g] = *(const uint2*)(Tc + (((unsigned)iA[g] << 7) + loff));
            uB[g] = *(const uint2*)(Tc + (((unsigned)iB[g] << 7) + loff));
        }
        #pragma unroll
        for (int g = 0; g < 4; ++g) {
            acc8(a0, uA[g]);
            acc8(a1, uB[g]);
        }
        i0 += 16;
        i1 += 16;
    }
    // ---- joint 4+4 ----
    while (i0 + 4 <= e0 && i1 + 4 <= e1) {
        int iA = csr_src[i0 + q];
        int iB = csr_src[i1 + q];
        uint2 uA = *(const uint2*)(Tc + (((unsigned)iA << 7) + loff));
        uint2 uB = *(const uint2*)(Tc + (((unsigned)iB << 7) + loff));
        acc8(a0, uA);
        acc8(a1, uB);
        i0 += 4;
        i1 += 4;
    }
    // ---- drain node0 ----
    for (; i0 + 16 <= e0; i0 += 16) {
        int idx[4];
        #pragma unroll
        for (int g = 0; g < 4; ++g) idx[g] = csr_src[i0 + g * 4 + q];
        uint2 u[4];
        #pragma unroll
        for (int g = 0; g < 4; ++g) u[g] = *(const uint2*)(Tc + (((unsigned)idx[g] << 7) + loff));
        #pragma unroll
        for (int g = 0; g < 4; ++g) acc8(a0, u[g]);
    }
    for (; i0 + 4 <= e0; i0 += 4) {
        int idx = csr_src[i0 + q];
        acc8(a0, *(const uint2*)(Tc + (((unsigned)idx << 7) + loff)));
    }
    if (e0 - i0 > 0) {
        int t = e0 - i0;
        int ii = i0 + q;
        if (ii >= e0) ii = e0 - 1;
        int idx = csr_src[ii];
        acc8m(a0, *(const uint2*)(Tc + (((unsigned)idx << 7) + loff)), (q < t) ? 1.0f : 0.0f);
    }
    // ---- drain node1 ----
    for (; i1 + 16 <= e1; i1 += 16) {
        int idx[4];
        #pragma unroll
        for (int g = 0; g < 4; ++g) idx[g] = csr_src[i1 + g * 4 + q];
        uint2 u[4];
        #pragma unroll
        for (int g = 0; g < 4; ++g) u[g] = *(const uint2*)(Tc + (((unsigned)idx[g] << 7) + loff));
        #pragma unroll
        for (int g = 0; g < 4; ++g) acc8(a1, u[g]);
    }
    for (; i1 + 4 <= e1; i1 += 4) {
        int idx = csr_src[i1 + q];
        acc8(a1, *(const uint2*)(Tc + (((unsigned)idx << 7) + loff)));
    }
    if (e1 - i1 > 0) {
        int t = e1 - i1;
        int ii = i1 + q;
        if (ii >= e1) ii = e1 - 1;
        int idx = csr_src[ii];
        acc8m(a1, *(const uint2*)(Tc + (((unsigned)idx << 7) + loff)), (q < t) ? 1.0f : 0.0f);
    }
    // ---- reduce quarter-partials ----
    #pragma unroll
    for (int j = 0; j < 8; ++j) {
        a0[j] += __shfl_xor(a0[j], 16);
        a0[j] += __shfl_xor(a0[j], 32);
        a1[j] += __shfl_xor(a1[j], 16);
        a1[j] += __shfl_xor(a1[j], 32);
    }
    // ---- epilogue: lane finishes feats f=8*l16+2q, f+1 for both nodes ----
    int f = 8 * l16 + 2 * q;
    float2 bb = *(const float2*)&bias[f];
    {
        float sx = (q < 2) ? ((q == 0) ? a0[0] : a0[2]) : ((q == 2) ? a0[4] : a0[6]);
        float sy = (q < 2) ? ((q == 0) ? a0[1] : a0[3]) : ((q == 2) ? a0[5] : a0[7]);
        float dv = dinv[n0];
        unsigned short selfu = *(const unsigned short*)(Tc + ((unsigned)n0 << 7) + f);
        f32x2 fs = __builtin_amdgcn_cvt_pk_f32_fp8((unsigned)selfu, false);
        float ox = tanhf(dv * (sx + fs[0]) + bb.x);
        float oy = tanhf(dv * (sy + fs[1]) + bb.y);
        ((unsigned*)Out)[n0 * 64 + (f >> 1)] = (unsigned)f2bf(ox) | ((unsigned)f2bf(oy) << 16);
    }
    if (has1) {
        float sx = (q < 2) ? ((q == 0) ? a1[0] : a1[2]) : ((q == 2) ? a1[4] : a1[6]);
        float sy = (q < 2) ? ((q == 0) ? a1[1] : a1[3]) : ((q == 2) ? a1[5] : a1[7]);
        float dv = dinv[n1];
        unsigned short selfu = *(const unsigned short*)(Tc + ((unsigned)n1 << 7) + f);
        f32x2 fs = __builtin_amdgcn_cvt_pk_f32_fp8((unsigned)selfu, false);
        float ox = tanhf(dv * (sx + fs[0]) + bb.x);
        float oy = tanhf(dv * (sy + fs[1]) + bb.y);
        ((unsigned*)Out)[n1 * 64 + (f >> 1)] = (unsigned)f2bf(ox) | ((unsigned)f2bf(oy) << 16);
    }
}

// ---------------- fused MFMA MLP head v2 (as R9) ----------------
__global__ __launch_bounds__(256, 2) void k_mlp(const unsigned short* __restrict__ H,
                                                const unsigned short* __restrict__ Wf1t,
                                                const float* __restrict__ bf1,
                                                const unsigned short* __restrict__ Wf2t,
                                                const float* __restrict__ bf2,
                                                const float* __restrict__ Wf3,
                                                const float* __restrict__ bf3,
                                                const int* __restrict__ batch,
                                                float* __restrict__ util_sum,
                                                int N, int G) {
    __shared__ unsigned short H2[4][16 * LDA];  // per-wave transpose slice
    __shared__ float gsum[8];
    const int tid = threadIdx.x;
    if (tid < 8) gsum[tid] = 0.0f;
    const int wave = tid >> 6, lane = tid & 63;
    const int m16 = lane & 15, q = lane >> 4;
    const int blk0 = blockIdx.x * 256;
    const int g0 = batch[min(blk0, N - 1)];
    bf16x8 w1[4][8], w2[4][2];
    #pragma unroll
    for (int kc = 0; kc < 4; ++kc) {
        #pragma unroll
        for (int t = 0; t < 8; ++t)
            w1[kc][t] = *(const bf16x8*)(Wf1t + ((t * 16 + m16) * 128 + kc * 32 + q * 8));
        #pragma unroll
        for (int t = 0; t < 2; ++t)
            w2[kc][t] = *(const bf16x8*)(Wf2t + ((t * 16 + m16) * 128 + kc * 32 + q * 8));
    }
    float b1v[8];
    #pragma unroll
    for (int t = 0; t < 8; ++t) b1v[t] = bf1[t * 16 + m16];
    const float b2lo = bf2[m16], b2hi = bf2[m16 + 16];
    const float w3lo = Wf3[m16], w3hi = Wf3[m16 + 16];
    const float bf3v = bf3[0];
    __syncthreads();  // gsum init visible before tile atomics
    unsigned short* h2s = H2[wave];
    const int wbase = blk0 + wave * 64;
    bf16x8 a[4];
    {
        int ar = wbase + m16;
        if (ar >= N) ar = N - 1;
        const bf16x8* arow = (const bf16x8*)(H + (size_t)ar * U + q * 8);
        #pragma unroll
        for (int kc = 0; kc < 4; ++kc) a[kc] = arow[kc * 4];
    }
    for (int tile = 0; tile < 4; ++tile) {
        const int row0 = wbase + tile * 16;
        bf16x8 an[4];
        if (tile < 3) {
            int ar = row0 + 16 + m16;
            if (ar >= N) ar = N - 1;
            const bf16x8* arow = (const bf16x8*)(H + (size_t)ar * U + q * 8);
            #pragma unroll
            for (int kc = 0; kc < 4; ++kc) an[kc] = arow[kc * 4];
        }
        f32x4 acc[8];
        #pragma unroll
        for (int t = 0; t < 8; ++t) acc[t] = (f32x4){0.f, 0.f, 0.f, 0.f};
        #pragma unroll
        for (int kc = 0; kc < 4; ++kc) {
            #pragma unroll
            for (int t = 0; t < 8; ++t)
                acc[t] = __builtin_amdgcn_mfma_f32_16x16x32_bf16(a[kc], w1[kc][t], acc[t], 0, 0, 0);
        }
        #pragma unroll
        for (int t = 0; t < 8; ++t) {
            #pragma unroll
            for (int r = 0; r < 4; ++r) {
                int lr = q * 4 + r;
                h2s[lr * LDA + t * 16 + m16] = f2bf(tanhf(acc[t][r] + b1v[t]));
            }
        }
        f32x4 acc2[2];
        acc2[0] = (f32x4){0.f, 0.f, 0.f, 0.f};
        acc2[1] = (f32x4){0.f, 0.f, 0.f, 0.f};
        const unsigned short* h2row = h2s + m16 * LDA + q * 8;
        #pragma unroll
        for (int kc = 0; kc < 4; ++kc) {
            bf16x8 af = *(const bf16x8*)(h2row + kc * 32);
            #pragma unroll
            for (int t = 0; t < 2; ++t)
                acc2[t] = __builtin_amdgcn_mfma_f32_16x16x32_bf16(af, w2[kc][t], acc2[t], 0, 0, 0);
        }
        #pragma unroll
        for (int r = 0; r < 4; ++r) {
            float t0 = tanhf(acc2[0][r] + b2lo);
            float t1 = tanhf(acc2[1][r] + b2hi);
            float v = t0 * w3lo + t1 * w3hi;
            v += __shfl_xor(v, 1);
            v += __shfl_xor(v, 2);
            v += __shfl_xor(v, 4);
            v += __shfl_xor(v, 8);
            if (m16 == 0) {
                int n = row0 + q * 4 + r;
                if (n < N) atomicAdd(&gsum[batch[n] - g0], v + bf3v);
            }
        }
        #pragma unroll
        for (int kc = 0; kc < 4; ++kc) a[kc] = an[kc];
    }
    __syncthreads();
    if (tid < 8) {
        int g = g0 + tid;
        if (g < G) {
            float s = gsum[tid];
            if (s != 0.0f) atomicAdd(&util_sum[g], s);
        }
    }
}

// ---------------- fused output: util + pair sigmoid ----------------
__global__ void k_out(const float* __restrict__ us, const int* __restrict__ cnt,
                      const int* __restrict__ ia, const int* __restrict__ ib,
                      float* __restrict__ out, int P, int G) {
    int t = blockIdx.x * 256 + threadIdx.x;
    if (t < G) out[P + t] = us[t] / fmaxf((float)cnt[t], 1.0f);
    if (t < P) {
        int a = ia[t], b = ib[t];
        float ua = us[a] / fmaxf((float)cnt[a], 1.0f);
        float ub = us[b] / fmaxf((float)cnt[b], 1.0f);
        out[t] = 1.0f / (1.0f + expf(-(ub - ua)));
    }
}

extern "C" void kernel_launch(void* const* d_in, const int* in_sizes, int n_in,
                              void* d_out, int out_size, void* d_ws, size_t ws_size,
                              hipStream_t stream) {
    const float* x     = (const float*)d_in[0];
    const int*   eidx  = (const int*)d_in[1];
    const int*   batch = (const int*)d_in[2];
    const int*   idx_a = (const int*)d_in[3];
    const int*   idx_b = (const int*)d_in[4];
    const float* W_in  = (const float*)d_in[5];
    const float* b_in  = (const float*)d_in[6];
    const float* W1    = (const float*)d_in[7];
    const float* b1    = (const float*)d_in[8];
    const float* W2    = (const float*)d_in[9];
    const float* b2    = (const float*)d_in[10];
    const float* Wf1   = (const float*)d_in[11];
    const float* bf1   = (const float*)d_in[12];
    const float* Wf2   = (const float*)d_in[13];
    const float* bf2   = (const float*)d_in[14];
    const float* Wf3   = (const float*)d_in[15];
    const float* bf3   = (const float*)d_in[16];
    float* out = (float*)d_out;

    const int N = in_sizes[0] / 9;
    const int E = in_sizes[1] / 2;
    const int P = in_sizes[3];
    const int G = out_size - P;

    const int* src = eidx;
    const int* dst = eidx + E;

    const int nw = (N + WSZ - 1) >> WB;  // level-2 windows (196 for N=100k)
    const int nb = (N + 1023) / 1024;
    const int nh = nw * NJ1;             // hist_g size
    const int nbh = (nh + 1023) / 1024;  // scan blocks for hist_g

    // ---- workspace carve-out ----
    char* ws = (char*)d_ws;
    size_t off = 0;
    auto take = [&](size_t bytes) -> void* {
        void* p = ws + off;
        off = (off + bytes + 255) & ~(size_t)255;
        return p;
    };
    int*   deg      = (int*)  take((size_t)N * 4);
    float* dinv     = (float*)take((size_t)N * 4);
    int*   rowptr   = (int*)  take((size_t)(N + 1) * 4);
    int*   bsum     = (int*)  take(256 * 4);
    int*   bsum2    = (int*)  take(256 * 4);
    int*   hist_g   = (int*)  take((size_t)nh * 4);
    int2*  eb       = (int2*) take((size_t)E * 8);
    int*   csr_src  = (int*)  take((size_t)E * 4);
    float* xs       = (float*)take((size_t)N * 16 * 4);  // 64B-padded rows
    float* xa       = (float*)take((size_t)N * 9 * 4);
    unsigned short* bufA = (unsigned short*)take((size_t)N * U * 2);  // bf16 acts
    unsigned char*  Tb   = (unsigned char*) take((size_t)N * U);      // fp8 table
    unsigned short* W1t  = (unsigned short*)take(128 * 128 * 2);
    unsigned short* W2t  = (unsigned short*)take(128 * 128 * 2);
    unsigned short* Wf1t = (unsigned short*)take(128 * 128 * 2);
    unsigned short* Wf2t = (unsigned short*)take(32 * 128 * 2);
    // zero-region: util_sum + cnt contiguous, single memset
    float* util_sum = (float*)take((size_t)G * 4 + (size_t)G * 4);
    int*   cnt      = (int*)(util_sum + G);
    (void)ws_size;

    hipMemsetAsync(util_sum, 0, (size_t)G * 8, stream);

    // ---- CSR build: two-level counting sort ----
    k_hist1<<<NJ1, 256, 0, stream>>>(dst, hist_g, E, nw);
    k_escan1<<<nbh, 256, 0, stream>>>(hist_g, bsum2, nh);
    k_escan2<<<nbh, 256, 0, stream>>>(hist_g, bsum2, nbh, nh);
    k_bucket<<<NJ1, 256, 0, stream>>>(src, dst, hist_g, eb, E, nw);
    k_deg2<<<nw, 256, 0, stream>>>(eb, hist_g, deg, E, nw, N);
    k_prep<<<(N + 255) / 256, 256, 0, stream>>>(deg, x, batch, W1, W2, Wf1, Wf2,
                                                dinv, xs, cnt, W1t, W2t, Wf1t, Wf2t, N);
    k_scan1<<<nb, 256, 0, stream>>>(deg, rowptr + 1, bsum, N);
    k_scan23<<<(N + 255) / 256, 256, 0, stream>>>(rowptr, bsum, nb, N);
    k_scatter2<<<nw, 256, 0, stream>>>(eb, hist_g, rowptr, csr_src, E, nw, N);

    const int gemmGrid = (N + 63) / 64;

    // ---- GCN layer 1: aggregate xs (R10 form), GEMM+bias+tanh -> bf16 ----
    k_aggx<<<(N + 15) / 16, 256, 0, stream>>>(xs, rowptr, csr_src, dinv, xa, N);
    k_gemm_in9<<<((size_t)N * U + 255) / 256, 256, 0, stream>>>(xa, W_in, b_in, bufA, N);

    const int aggbGrid = (N + 7) / 8;  // 2 nodes/wave, 8 nodes/block

    // ---- GCN layer 2 ----
    k_gemm_mfma<<<gemmGrid, 256, 0, stream>>>(bufA, W1t, dinv, Tb, N);
    k_aggb<<<aggbGrid, 256, 0, stream>>>(Tb, rowptr, csr_src, dinv, b1, bufA, N);
    // ---- GCN layer 3 ----
    k_gemm_mfma<<<gemmGrid, 256, 0, stream>>>(bufA, W2t, dinv, Tb, N);
    k_aggb<<<aggbGrid, 256, 0, stream>>>(Tb, rowptr, csr_src, dinv, b2, bufA, N);

    // ---- MLP head + pooled sums (256 nodes/block) ----
    k_mlp<<<(N + 255) / 256, 256, 0, stream>>>(bufA, Wf1t, bf1, Wf2t, bf2, Wf3, bf3,
                                               batch, util_sum, N, G);

    // ---- fused util + pairs ----
    int mx = (P > G ? P : G);
    k_out<<<(mx + 255) / 256, 256, 0, stream>>>(util_sum, cnt, idx_a, idx_b, out, P, G);
}

// Round 14
// 431.977 us; speedup vs baseline: 1.0707x; 1.0121x over previous
//
#include <hip/hip_runtime.h>
#include <hip/hip_bf16.h>
#include <math.h>

// ---------------------------------------------------------------------------
// RankGNN R14: xs table -> bf16 32B rows (halves aggx gather bytes); fast
// exp-based tanh (clamp +-9) replacing libm tanhf in all hot epilogues.
// Rest as R13.
// ---------------------------------------------------------------------------

#define U 128
#define LDA 136    // LDS row stride in bf16 elems (128 + 8 pad)
#define WB 9       // log2(window) = 512 nodes per level-2 window
#define WSZ 512
#define NJ1 256    // level-1 blocks (edge chunks)

typedef __attribute__((ext_vector_type(8))) short bf16x8;
typedef __attribute__((ext_vector_type(4))) float f32x4;
typedef __attribute__((ext_vector_type(2))) float f32x2;

__device__ __forceinline__ unsigned short f2bf(float f) {
    unsigned u = __float_as_uint(f);
    unsigned r = (u + 0x7fffu + ((u >> 16) & 1u)) >> 16;  // RNE
    return (unsigned short)r;
}
__device__ __forceinline__ float bf2f(unsigned short u) {
    return __uint_as_float((unsigned)u << 16);
}
__device__ __forceinline__ unsigned char f2fp8(float v) {
    return (unsigned char)(__builtin_amdgcn_cvt_pk_fp8_f32(v, v, 0, false) & 0xff);
}
__device__ __forceinline__ float ftanh(float x) {
    float cx = fminf(fmaxf(x, -9.0f), 9.0f);
    float t = __expf(2.0f * cx);
    return (t - 1.0f) / (t + 1.0f);
}
__device__ __forceinline__ void acc8(float* a, uint2 u) {
    f32x2 f0 = __builtin_amdgcn_cvt_pk_f32_fp8(u.x, false);
    f32x2 f1 = __builtin_amdgcn_cvt_pk_f32_fp8(u.x, true);
    f32x2 f2 = __builtin_amdgcn_cvt_pk_f32_fp8(u.y, false);
    f32x2 f3 = __builtin_amdgcn_cvt_pk_f32_fp8(u.y, true);
    a[0] += f0[0]; a[1] += f0[1]; a[2] += f1[0]; a[3] += f1[1];
    a[4] += f2[0]; a[5] += f2[1]; a[6] += f3[0]; a[7] += f3[1];
}
__device__ __forceinline__ void acc8m(float* a, uint2 u, float m) {
    f32x2 f0 = __builtin_amdgcn_cvt_pk_f32_fp8(u.x, false);
    f32x2 f1 = __builtin_amdgcn_cvt_pk_f32_fp8(u.x, true);
    f32x2 f2 = __builtin_amdgcn_cvt_pk_f32_fp8(u.y, false);
    f32x2 f3 = __builtin_amdgcn_cvt_pk_f32_fp8(u.y, true);
    a[0] += m * f0[0]; a[1] += m * f0[1]; a[2] += m * f1[0]; a[3] += m * f1[1];
    a[4] += m * f2[0]; a[5] += m * f2[1]; a[6] += m * f3[0]; a[7] += m * f3[1];
}

// ---------------- level-1: per-chunk window histogram ----------------
__global__ __launch_bounds__(256) void k_hist1(const int* __restrict__ dst,
                                               int* __restrict__ hist_g, int E, int nw) {
    __shared__ int h[256];  // nw <= 256
    int b = blockIdx.x;
    for (int i = threadIdx.x; i < nw; i += 256) h[i] = 0;
    __syncthreads();
    int ch = (E + NJ1 - 1) / NJ1;
    int e0 = b * ch, e1 = min(e0 + ch, E);
    for (int e = e0 + threadIdx.x; e < e1; e += 256)
        atomicAdd(&h[dst[e] >> WB], 1);
    __syncthreads();
    for (int w = threadIdx.x; w < nw; w += 256) hist_g[w * NJ1 + b] = h[w];
}

// ---------------- generic parallel exclusive scan (in place) ----------------
__global__ __launch_bounds__(256) void k_escan1(int* __restrict__ a,
                                                int* __restrict__ bsum, int n) {
    __shared__ int sc[256];
    int t = threadIdx.x, b = blockIdx.x;
    int base = b * 1024 + t * 4;
    int v[4];
    int s = 0;
    #pragma unroll
    for (int j = 0; j < 4; ++j) {
        int idx = base + j;
        int d = (idx < n) ? a[idx] : 0;
        v[j] = s;  // exclusive within thread
        s += d;
    }
    sc[t] = s;
    __syncthreads();
    for (int off = 1; off < 256; off <<= 1) {
        int x = (t >= off) ? sc[t - off] : 0;
        __syncthreads();
        sc[t] += x;
        __syncthreads();
    }
    int excl = sc[t] - s;
    #pragma unroll
    for (int j = 0; j < 4; ++j) {
        int idx = base + j;
        if (idx < n) a[idx] = v[j] + excl;
    }
    if (t == 255) bsum[b] = sc[255];
}

__global__ __launch_bounds__(256) void k_escan2(int* __restrict__ a,
                                                const int* __restrict__ bsum,
                                                int nb, int n) {
    __shared__ int sc[256];
    int t = threadIdx.x;
    int v = (t < nb) ? bsum[t] : 0;
    sc[t] = v;
    __syncthreads();
    for (int off = 1; off < 256; off <<= 1) {
        int u = (t >= off) ? sc[t - off] : 0;
        __syncthreads();
        sc[t] += u;
        __syncthreads();
    }
    int myoff = (blockIdx.x > 0) ? (sc[blockIdx.x] - bsum[blockIdx.x]) : 0;
    int base = blockIdx.x * 1024;
    #pragma unroll
    for (int j = 0; j < 4; ++j) {
        int idx = base + t + j * 256;
        if (idx < n) a[idx] += myoff;
    }
}

// ---------------- level-1: bucket edges window-major ----------------
__global__ __launch_bounds__(256) void k_bucket(const int* __restrict__ src,
                                                const int* __restrict__ dst,
                                                const int* __restrict__ hist_g,
                                                int2* __restrict__ eb, int E, int nw) {
    __shared__ int lcur[256];
    int b = blockIdx.x;
    for (int w = threadIdx.x; w < nw; w += 256) lcur[w] = hist_g[w * NJ1 + b];
    __syncthreads();
    int ch = (E + NJ1 - 1) / NJ1;
    int e0 = b * ch, e1 = min(e0 + ch, E);
    for (int e = e0 + threadIdx.x; e < e1; e += 256) {
        int d = dst[e];
        int pos = atomicAdd(&lcur[d >> WB], 1);
        eb[pos] = make_int2(src[e], d);
    }
}

// ---------------- level-2: per-window degree histogram -> deg ---------------
__global__ __launch_bounds__(256) void k_deg2(const int2* __restrict__ eb,
                                              const int* __restrict__ hist_g,
                                              int* __restrict__ deg, int E, int nw, int N) {
    __shared__ int h[WSZ];
    int w = blockIdx.x;
    h[threadIdx.x] = 0;
    h[threadIdx.x + 256] = 0;
    __syncthreads();
    int s0 = hist_g[w * NJ1];
    int s1 = (w + 1 < nw) ? hist_g[(w + 1) * NJ1] : E;
    for (int i = s0 + threadIdx.x; i < s1; i += 256)
        atomicAdd(&h[eb[i].y & (WSZ - 1)], 1);
    __syncthreads();
    int base = w << WB;
    if (base + threadIdx.x < N) deg[base + threadIdx.x] = h[threadIdx.x];
    if (base + 256 + threadIdx.x < N) deg[base + 256 + threadIdx.x] = h[256 + threadIdx.x];
}

// ---------------- rowptr scan ----------------
__global__ __launch_bounds__(256) void k_scan1(const int* __restrict__ deg,
                                               int* __restrict__ rowptr1,
                                               int* __restrict__ bsum, int N) {
    __shared__ int sc[256];
    int t = threadIdx.x, b = blockIdx.x;
    int base = b * 1024 + t * 4;
    int v[4];
    int s = 0;
    #pragma unroll
    for (int j = 0; j < 4; ++j) {
        int idx = base + j;
        int d = (idx < N) ? deg[idx] : 0;
        s += d;
        v[j] = s;
    }
    sc[t] = s;
    __syncthreads();
    for (int off = 1; off < 256; off <<= 1) {
        int x = (t >= off) ? sc[t - off] : 0;
        __syncthreads();
        sc[t] += x;
        __syncthreads();
    }
    int excl = sc[t] - s;
    #pragma unroll
    for (int j = 0; j < 4; ++j) {
        int idx = base + j;
        if (idx < N) rowptr1[idx] = v[j] + excl;
    }
    if (t == 255) bsum[b] = sc[255];
}

__global__ __launch_bounds__(256) void k_scan23(int* __restrict__ rowptr,
                                                const int* __restrict__ bsum,
                                                int nb, int N) {
    __shared__ int sc[256];
    __shared__ int bo[256];
    int t = threadIdx.x;
    int v = (t < nb) ? bsum[t] : 0;
    sc[t] = v;
    __syncthreads();
    for (int off = 1; off < 256; off <<= 1) {
        int u = (t >= off) ? sc[t - off] : 0;
        __syncthreads();
        sc[t] += u;
        __syncthreads();
    }
    bo[t] = sc[t] - v;  // exclusive
    __syncthreads();
    int i = blockIdx.x * 256 + t;
    if (i < N) rowptr[1 + i] += bo[i >> 10];
    if (i == 0) rowptr[0] = 0;
}

// ---------------- level-2: single-writer CSR scatter ----------------
__global__ __launch_bounds__(256) void k_scatter2(const int2* __restrict__ eb,
                                                  const int* __restrict__ hist_g,
                                                  const int* __restrict__ rowptr,
                                                  int* __restrict__ csr_src,
                                                  int E, int nw, int N) {
    __shared__ int cur[WSZ];
    int w = blockIdx.x;
    int base = w << WB;
    int i0 = base + threadIdx.x, i1 = base + 256 + threadIdx.x;
    cur[threadIdx.x] = (i0 < N) ? rowptr[i0] : 0;
    cur[threadIdx.x + 256] = (i1 < N) ? rowptr[i1] : 0;
    __syncthreads();
    int s0 = hist_g[w * NJ1];
    int s1 = (w + 1 < nw) ? hist_g[(w + 1) * NJ1] : E;
    for (int i = s0 + threadIdx.x; i < s1; i += 256) {
        int2 e = eb[i];
        int pos = atomicAdd(&cur[e.y & (WSZ - 1)], 1);
        csr_src[pos] = e.x;
    }
}

// ---------------- fused prep: dinv, xs (bf16 32B rows), counts, weights -----
__global__ __launch_bounds__(256) void k_prep(const int* __restrict__ deg,
                                              const float* __restrict__ x,
                                              const int* __restrict__ batch,
                                              const float* __restrict__ W1,
                                              const float* __restrict__ W2,
                                              const float* __restrict__ Wf1,
                                              const float* __restrict__ Wf2,
                                              float* __restrict__ dinv,
                                              unsigned short* __restrict__ xs,
                                              int* __restrict__ cnt,
                                              unsigned short* __restrict__ W1t,
                                              unsigned short* __restrict__ W2t,
                                              unsigned short* __restrict__ Wf1t,
                                              unsigned short* __restrict__ Wf2t, int N) {
    int t = blockIdx.x * 256 + threadIdx.x;
    if (t < N) {
        float dv = rsqrtf((float)deg[t] + 1.0f);
        dinv[t] = dv;
        #pragma unroll
        for (int k = 0; k < 9; ++k) xs[t * 16 + k] = f2bf(x[t * 9 + k] * dv);
        #pragma unroll
        for (int k = 9; k < 16; ++k) xs[t * 16 + k] = 0;
        atomicAdd(&cnt[batch[t]], 1);
    }
    if (t < 16384) {
        int n = t >> 7, k = t & 127;
        W1t[n * 128 + k] = f2bf(W1[k * 128 + n]);
        Wf1t[n * 128 + k] = f2bf(Wf1[k * 128 + n]);
    } else if (t < 32768) {
        int i = t - 16384, n = i >> 7, k = i & 127;
        W2t[n * 128 + k] = f2bf(W2[k * 128 + n]);
    } else if (t < 36864) {
        int i = t - 32768, n = i >> 7, k = i & 127;
        Wf2t[n * 128 + k] = f2bf(Wf2[k * 32 + n]);
    }
}

// ---------------- layer-1: aggregate xs (bf16 32B rows) ----------------
__global__ __launch_bounds__(256) void k_aggx(const unsigned short* __restrict__ xs,
                                              const int* __restrict__ rowptr,
                                              const int* __restrict__ csr_src,
                                              const float* __restrict__ dinv,
                                              float* __restrict__ xa, int N) {
    int node = blockIdx.x * 16 + (threadIdx.x >> 4);
    if (node >= N) return;
    int lane = threadIdx.x & 15;
    int s = rowptr[node], e = rowptr[node + 1];
    float a0 = 0.0f, a1 = 0.0f, a2 = 0.0f, a3 = 0.0f;
    int i = s;
    for (; i + 4 <= e; i += 4) {
        int s0 = csr_src[i], s1 = csr_src[i + 1];
        int s2 = csr_src[i + 2], s3 = csr_src[i + 3];
        a0 += bf2f(xs[s0 * 16 + lane]);
        a1 += bf2f(xs[s1 * 16 + lane]);
        a2 += bf2f(xs[s2 * 16 + lane]);
        a3 += bf2f(xs[s3 * 16 + lane]);
    }
    for (; i < e; ++i) {
        int s0 = csr_src[i];
        a0 += bf2f(xs[s0 * 16 + lane]);
    }
    if (lane < 9) {
        float dv = dinv[node];
        xa[node * 9 + lane] = dv * (a0 + a1 + a2 + a3 + bf2f(xs[node * 16 + lane]));
    }
}

// ---------------- layer-1 GEMM: bf16(tanh(xa @ W_in + b)) ----------------
__global__ void k_gemm_in9(const float* __restrict__ xa, const float* __restrict__ Wi,
                           const float* __restrict__ bi, unsigned short* __restrict__ T,
                           int N) {
    int t = blockIdx.x * 256 + threadIdx.x;
    if (t < N * U) {
        int n = t >> 7, c = t & 127;
        const float* xr = xa + n * 9;
        float acc = bi[c];
        #pragma unroll
        for (int k = 0; k < 9; ++k) acc += xr[k] * Wi[k * U + c];
        T[t] = f2bf(ftanh(acc));
    }
}

// ---------------- MFMA GEMM -> fp8 table: Ts = fp8(dinv * (A @ Wt^T)) -------
__global__ __launch_bounds__(256) void k_gemm_mfma(const unsigned short* __restrict__ A,
                                                   const unsigned short* __restrict__ Wt,
                                                   const float* __restrict__ dinv,
                                                   unsigned char* __restrict__ Out, int N) {
    const int tid = threadIdx.x;
    const int wave = tid >> 6, lane = tid & 63;
    const int m16 = lane & 15, q = lane >> 4;
    const int row0 = blockIdx.x * 64 + wave * 16;
    int arow_idx = row0 + m16;
    if (arow_idx >= N) arow_idx = N - 1;  // clamp; OOB outputs are guarded
    const bf16x8* arow = (const bf16x8*)(A + (size_t)arow_idx * U + q * 8);
    f32x4 acc[8];
    #pragma unroll
    for (int t = 0; t < 8; ++t) acc[t] = (f32x4){0.f, 0.f, 0.f, 0.f};
    #pragma unroll
    for (int kc = 0; kc < 4; ++kc) {
        bf16x8 af = arow[kc * 4];
        #pragma unroll
        for (int t = 0; t < 8; ++t) {
            bf16x8 bfr = *(const bf16x8*)(Wt + ((t * 16 + m16) * 128 + kc * 32 + q * 8));
            acc[t] = __builtin_amdgcn_mfma_f32_16x16x32_bf16(af, bfr, acc[t], 0, 0, 0);
        }
    }
    float dv[4];
    #pragma unroll
    for (int r = 0; r < 4; ++r) {
        int gr = row0 + q * 4 + r;
        dv[r] = (gr < N) ? dinv[gr] : 0.0f;
    }
    #pragma unroll
    for (int t = 0; t < 8; ++t) {
        #pragma unroll
        for (int r = 0; r < 4; ++r) {
            int gr = row0 + q * 4 + r;
            if (gr < N) Out[(size_t)gr * U + t * 16 + m16] = f2fp8(acc[t][r] * dv[r]);
        }
    }
}

// ---------------- aggregation (fp8 table): 2 nodes/wave, 4 edges/gather -----
__global__ __launch_bounds__(256) void k_aggb(const unsigned char* __restrict__ Tb,
                                              const int* __restrict__ rowptr,
                                              const int* __restrict__ csr_src,
                                              const float* __restrict__ dinv,
                                              const float* __restrict__ bias,
                                              unsigned short* __restrict__ Out, int N) {
    int n0 = blockIdx.x * 8 + ((threadIdx.x >> 6) << 1);
    if (n0 >= N) return;
    int n1 = n0 + 1;
    bool has1 = (n1 < N);
    if (!has1) n1 = n0;
    int lane = threadIdx.x & 63;
    int q = lane >> 4, l16 = lane & 15;
    const char* Tc = (const char*)Tb;
    const unsigned loff = (unsigned)l16 << 3;
    float a0[8] = {0.f, 0.f, 0.f, 0.f, 0.f, 0.f, 0.f, 0.f};
    float a1[8] = {0.f, 0.f, 0.f, 0.f, 0.f, 0.f, 0.f, 0.f};
    int s0 = __builtin_amdgcn_readfirstlane(rowptr[n0]);
    int e0 = __builtin_amdgcn_readfirstlane(rowptr[n0 + 1]);
    int s1 = __builtin_amdgcn_readfirstlane(rowptr[n1]);
    int e1 = __builtin_amdgcn_readfirstlane(rowptr[n1 + 1]);
    int i0 = s0, i1 = s1;
    // ---- joint 16+16: 8 gathers in flight ----
    while (i0 + 16 <= e0 && i1 + 16 <= e1) {
        int iA[4], iB[4];
        #pragma unroll
        for (int g = 0; g < 4; ++g) {
            iA[g] = csr_src[i0 + g * 4 + q];
            iB[g] = csr_src[i1 + g * 4 + q];
        }
        uint2 uA[4], uB[4];
        #pragma unroll
        for (int g = 0; g < 4; ++g) {
            uA[g] = *(const uint2*)(Tc + (((unsigned)iA[g] << 7) + loff));
            uB[g] = *(const uint2*)(Tc + (((unsigned)iB[g] << 7) + loff));
        }
        #pragma unroll
        for (int g = 0; g < 4; ++g) {
            acc8(a0, uA[g]);
            acc8(a1, uB[g]);
        }
        i0 += 16;
        i1 += 16;
    }
    // ---- joint 4+4 ----
    while (i0 + 4 <= e0 && i1 + 4 <= e1) {
        int iA = csr_src[i0 + q];
        int iB = csr_src[i1 + q];
        uint2 uA = *(const uint2*)(Tc + (((unsigned)iA << 7) + loff));
        uint2 uB = *(const uint2*)(Tc + (((unsigned)iB << 7) + loff));
        acc8(a0, uA);
        acc8(a1, uB);
        i0 += 4;
        i1 += 4;
    }
    // ---- drain node0 ----
    for (; i0 + 16 <= e0; i0 += 16) {
        int idx[4];
        #pragma unroll
        for (int g = 0; g < 4; ++g) idx[g] = csr_src[i0 + g * 4 + q];
        uint2 u[4];
        #pragma unroll
        for (int g = 0; g < 4; ++g) u[g] = *(const uint2*)(Tc + (((unsigned)idx[g] << 7) + loff));
        #pragma unroll
        for (int g = 0; g < 4; ++g) acc8(a0, u[g]);
    }
    for (; i0 + 4 <= e0; i0 += 4) {
        int idx = csr_src[i0 + q];
        acc8(a0, *(const uint2*)(Tc + (((unsigned)idx << 7) + loff)));
    }
    if (e0 - i0 > 0) {
        int t = e0 - i0;
        int ii = i0 + q;
        if (ii >= e0) ii = e0 - 1;
        int idx = csr_src[ii];
        acc8m(a0, *(const uint2*)(Tc + (((unsigned)idx << 7) + loff)), (q < t) ? 1.0f : 0.0f);
    }
    // ---- drain node1 ----
    for (; i1 + 16 <= e1; i1 += 16) {
        int idx[4];
        #pragma unroll
        for (int g = 0; g < 4; ++g) idx[g] = csr_src[i1 + g * 4 + q];
        uint2 u[4];
        #pragma unroll
        for (int g = 0; g < 4; ++g) u[g] = *(const uint2*)(Tc + (((unsigned)idx[g] << 7) + loff));
        #pragma unroll
        for (int g = 0; g < 4; ++g) acc8(a1, u[g]);
    }
    for (; i1 + 4 <= e1; i1 += 4) {
        int idx = csr_src[i1 + q];
        acc8(a1, *(const uint2*)(Tc + (((unsigned)idx << 7) + loff)));
    }
    if (e1 - i1 > 0) {
        int t = e1 - i1;
        int ii = i1 + q;
        if (ii >= e1) ii = e1 - 1;
        int idx = csr_src[ii];
        acc8m(a1, *(const uint2*)(Tc + (((unsigned)idx << 7) + loff)), (q < t) ? 1.0f : 0.0f);
    }
    // ---- reduce quarter-partials ----
    #pragma unroll
    for (int j = 0; j < 8; ++j) {
        a0[j] += __shfl_xor(a0[j], 16);
        a0[j] += __shfl_xor(a0[j], 32);
        a1[j] += __shfl_xor(a1[j], 16);
        a1[j] += __shfl_xor(a1[j], 32);
    }
    // ---- epilogue: lane finishes feats f=8*l16+2q, f+1 for both nodes ----
    int f = 8 * l16 + 2 * q;
    float2 bb = *(const float2*)&bias[f];
    {
        float sx = (q < 2) ? ((q == 0) ? a0[0] : a0[2]) : ((q == 2) ? a0[4] : a0[6]);
        float sy = (q < 2) ? ((q == 0) ? a0[1] : a0[3]) : ((q == 2) ? a0[5] : a0[7]);
        float dv = dinv[n0];
        unsigned short selfu = *(const unsigned short*)(Tc + ((unsigned)n0 << 7) + f);
        f32x2 fs = __builtin_amdgcn_cvt_pk_f32_fp8((unsigned)selfu, false);
        float ox = ftanh(dv * (sx + fs[0]) + bb.x);
        float oy = ftanh(dv * (sy + fs[1]) + bb.y);
        ((unsigned*)Out)[n0 * 64 + (f >> 1)] = (unsigned)f2bf(ox) | ((unsigned)f2bf(oy) << 16);
    }
    if (has1) {
        float sx = (q < 2) ? ((q == 0) ? a1[0] : a1[2]) : ((q == 2) ? a1[4] : a1[6]);
        float sy = (q < 2) ? ((q == 0) ? a1[1] : a1[3]) : ((q == 2) ? a1[5] : a1[7]);
        float dv = dinv[n1];
        unsigned short selfu = *(const unsigned short*)(Tc + ((unsigned)n1 << 7) + f);
        f32x2 fs = __builtin_amdgcn_cvt_pk_f32_fp8((unsigned)selfu, false);
        float ox = ftanh(dv * (sx + fs[0]) + bb.x);
        float oy = ftanh(dv * (sy + fs[1]) + bb.y);
        ((unsigned*)Out)[n1 * 64 + (f >> 1)] = (unsigned)f2bf(ox) | ((unsigned)f2bf(oy) << 16);
    }
}

// ---------------- fused MFMA MLP head v2 (as R9) ----------------
__global__ __launch_bounds__(256, 2) void k_mlp(const unsigned short* __restrict__ H,
                                                const unsigned short* __restrict__ Wf1t,
                                                const float* __restrict__ bf1,
                                                const unsigned short* __restrict__ Wf2t,
                                                const float* __restrict__ bf2,
                                                const float* __restrict__ Wf3,
                                                const float* __restrict__ bf3,
                                                const int* __restrict__ batch,
                                                float* __restrict__ util_sum,
                                                int N, int G) {
    __shared__ unsigned short H2[4][16 * LDA];  // per-wave transpose slice
    __shared__ float gsum[8];
    const int tid = threadIdx.x;
    if (tid < 8) gsum[tid] = 0.0f;
    const int wave = tid >> 6, lane = tid & 63;
    const int m16 = lane & 15, q = lane >> 4;
    const int blk0 = blockIdx.x * 256;
    const int g0 = batch[min(blk0, N - 1)];
    bf16x8 w1[4][8], w2[4][2];
    #pragma unroll
    for (int kc = 0; kc < 4; ++kc) {
        #pragma unroll
        for (int t = 0; t < 8; ++t)
            w1[kc][t] = *(const bf16x8*)(Wf1t + ((t * 16 + m16) * 128 + kc * 32 + q * 8));
        #pragma unroll
        for (int t = 0; t < 2; ++t)
            w2[kc][t] = *(const bf16x8*)(Wf2t + ((t * 16 + m16) * 128 + kc * 32 + q * 8));
    }
    float b1v[8];
    #pragma unroll
    for (int t = 0; t < 8; ++t) b1v[t] = bf1[t * 16 + m16];
    const float b2lo = bf2[m16], b2hi = bf2[m16 + 16];
    const float w3lo = Wf3[m16], w3hi = Wf3[m16 + 16];
    const float bf3v = bf3[0];
    __syncthreads();  // gsum init visible before tile atomics
    unsigned short* h2s = H2[wave];
    const int wbase = blk0 + wave * 64;
    bf16x8 a[4];
    {
        int ar = wbase + m16;
        if (ar >= N) ar = N - 1;
        const bf16x8* arow = (const bf16x8*)(H + (size_t)ar * U + q * 8);
        #pragma unroll
        for (int kc = 0; kc < 4; ++kc) a[kc] = arow[kc * 4];
    }
    for (int tile = 0; tile < 4; ++tile) {
        const int row0 = wbase + tile * 16;
        bf16x8 an[4];
        if (tile < 3) {
            int ar = row0 + 16 + m16;
            if (ar >= N) ar = N - 1;
            const bf16x8* arow = (const bf16x8*)(H + (size_t)ar * U + q * 8);
            #pragma unroll
            for (int kc = 0; kc < 4; ++kc) an[kc] = arow[kc * 4];
        }
        f32x4 acc[8];
        #pragma unroll
        for (int t = 0; t < 8; ++t) acc[t] = (f32x4){0.f, 0.f, 0.f, 0.f};
        #pragma unroll
        for (int kc = 0; kc < 4; ++kc) {
            #pragma unroll
            for (int t = 0; t < 8; ++t)
                acc[t] = __builtin_amdgcn_mfma_f32_16x16x32_bf16(a[kc], w1[kc][t], acc[t], 0, 0, 0);
        }
        #pragma unroll
        for (int t = 0; t < 8; ++t) {
            #pragma unroll
            for (int r = 0; r < 4; ++r) {
                int lr = q * 4 + r;
                h2s[lr * LDA + t * 16 + m16] = f2bf(ftanh(acc[t][r] + b1v[t]));
            }
        }
        f32x4 acc2[2];
        acc2[0] = (f32x4){0.f, 0.f, 0.f, 0.f};
        acc2[1] = (f32x4){0.f, 0.f, 0.f, 0.f};
        const unsigned short* h2row = h2s + m16 * LDA + q * 8;
        #pragma unroll
        for (int kc = 0; kc < 4; ++kc) {
            bf16x8 af = *(const bf16x8*)(h2row + kc * 32);
            #pragma unroll
            for (int t = 0; t < 2; ++t)
                acc2[t] = __builtin_amdgcn_mfma_f32_16x16x32_bf16(af, w2[kc][t], acc2[t], 0, 0, 0);
        }
        #pragma unroll
        for (int r = 0; r < 4; ++r) {
            float t0 = ftanh(acc2[0][r] + b2lo);
            float t1 = ftanh(acc2[1][r] + b2hi);
            float v = t0 * w3lo + t1 * w3hi;
            v += __shfl_xor(v, 1);
            v += __shfl_xor(v, 2);
            v += __shfl_xor(v, 4);
            v += __shfl_xor(v, 8);
            if (m16 == 0) {
                int n = row0 + q * 4 + r;
                if (n < N) atomicAdd(&gsum[batch[n] - g0], v + bf3v);
            }
        }
        #pragma unroll
        for (int kc = 0; kc < 4; ++kc) a[kc] = an[kc];
    }
    __syncthreads();
    if (tid < 8) {
        int g = g0 + tid;
        if (g < G) {
            float s = gsum[tid];
            if (s != 0.0f) atomicAdd(&util_sum[g], s);
        }
    }
}

// ---------------- fused output: util + pair sigmoid ----------------
__global__ void k_out(const float* __restrict__ us, const int* __restrict__ cnt,
                      const int* __restrict__ ia, const int* __restrict__ ib,
                      float* __restrict__ out, int P, int G) {
    int t = blockIdx.x * 256 + threadIdx.x;
    if (t < G) out[P + t] = us[t] / fmaxf((float)cnt[t], 1.0f);
    if (t < P) {
        int a = ia[t], b = ib[t];
        float ua = us[a] / fmaxf((float)cnt[a], 1.0f);
        float ub = us[b] / fmaxf((float)cnt[b], 1.0f);
        out[t] = 1.0f / (1.0f + expf(-(ub - ua)));
    }
}

extern "C" void kernel_launch(void* const* d_in, const int* in_sizes, int n_in,
                              void* d_out, int out_size, void* d_ws, size_t ws_size,
                              hipStream_t stream) {
    const float* x     = (const float*)d_in[0];
    const int*   eidx  = (const int*)d_in[1];
    const int*   batch = (const int*)d_in[2];
    const int*   idx_a = (const int*)d_in[3];
    const int*   idx_b = (const int*)d_in[4];
    const float* W_in  = (const float*)d_in[5];
    const float* b_in  = (const float*)d_in[6];
    const float* W1    = (const float*)d_in[7];
    const float* b1    = (const float*)d_in[8];
    const float* W2    = (const float*)d_in[9];
    const float* b2    = (const float*)d_in[10];
    const float* Wf1   = (const float*)d_in[11];
    const float* bf1   = (const float*)d_in[12];
    const float* Wf2   = (const float*)d_in[13];
    const float* bf2   = (const float*)d_in[14];
    const float* Wf3   = (const float*)d_in[15];
    const float* bf3   = (const float*)d_in[16];
    float* out = (float*)d_out;

    const int N = in_sizes[0] / 9;
    const int E = in_sizes[1] / 2;
    const int P = in_sizes[3];
    const int G = out_size - P;

    const int* src = eidx;
    const int* dst = eidx + E;

    const int nw = (N + WSZ - 1) >> WB;  // level-2 windows (196 for N=100k)
    const int nb = (N + 1023) / 1024;
    const int nh = nw * NJ1;             // hist_g size
    const int nbh = (nh + 1023) / 1024;  // scan blocks for hist_g

    // ---- workspace carve-out ----
    char* ws = (char*)d_ws;
    size_t off = 0;
    auto take = [&](size_t bytes) -> void* {
        void* p = ws + off;
        off = (off + bytes + 255) & ~(size_t)255;
        return p;
    };
    int*   deg      = (int*)  take((size_t)N * 4);
    float* dinv     = (float*)take((size_t)N * 4);
    int*   rowptr   = (int*)  take((size_t)(N + 1) * 4);
    int*   bsum     = (int*)  take(256 * 4);
    int*   bsum2    = (int*)  take(256 * 4);
    int*   hist_g   = (int*)  take((size_t)nh * 4);
    int2*  eb       = (int2*) take((size_t)E * 8);
    int*   csr_src  = (int*)  take((size_t)E * 4);
    unsigned short* xs = (unsigned short*)take((size_t)N * 16 * 2);  // bf16 32B rows
    float* xa       = (float*)take((size_t)N * 9 * 4);
    unsigned short* bufA = (unsigned short*)take((size_t)N * U * 2);  // bf16 acts
    unsigned char*  Tb   = (unsigned char*) take((size_t)N * U);      // fp8 table
    unsigned short* W1t  = (unsigned short*)take(128 * 128 * 2);
    unsigned short* W2t  = (unsigned short*)take(128 * 128 * 2);
    unsigned short* Wf1t = (unsigned short*)take(128 * 128 * 2);
    unsigned short* Wf2t = (unsigned short*)take(32 * 128 * 2);
    // zero-region: util_sum + cnt contiguous, single memset
    float* util_sum = (float*)take((size_t)G * 4 + (size_t)G * 4);
    int*   cnt      = (int*)(util_sum + G);
    (void)ws_size;

    hipMemsetAsync(util_sum, 0, (size_t)G * 8, stream);

    // ---- CSR build: two-level counting sort ----
    k_hist1<<<NJ1, 256, 0, stream>>>(dst, hist_g, E, nw);
    k_escan1<<<nbh, 256, 0, stream>>>(hist_g, bsum2, nh);
    k_escan2<<<nbh, 256, 0, stream>>>(hist_g, bsum2, nbh, nh);
    k_bucket<<<NJ1, 256, 0, stream>>>(src, dst, hist_g, eb, E, nw);
    k_deg2<<<nw, 256, 0, stream>>>(eb, hist_g, deg, E, nw, N);
    k_prep<<<(N + 255) / 256, 256, 0, stream>>>(deg, x, batch, W1, W2, Wf1, Wf2,
                                                dinv, xs, cnt, W1t, W2t, Wf1t, Wf2t, N);
    k_scan1<<<nb, 256, 0, stream>>>(deg, rowptr + 1, bsum, N);
    k_scan23<<<(N + 255) / 256, 256, 0, stream>>>(rowptr, bsum, nb, N);
    k_scatter2<<<nw, 256, 0, stream>>>(eb, hist_g, rowptr, csr_src, E, nw, N);

    const int gemmGrid = (N + 63) / 64;

    // ---- GCN layer 1: aggregate xs (bf16 rows), GEMM+bias+tanh -> bf16 ----
    k_aggx<<<(N + 15) / 16, 256, 0, stream>>>(xs, rowptr, csr_src, dinv, xa, N);
    k_gemm_in9<<<((size_t)N * U + 255) / 256, 256, 0, stream>>>(xa, W_in, b_in, bufA, N);

    const int aggbGrid = (N + 7) / 8;  // 2 nodes/wave, 8 nodes/block

    // ---- GCN layer 2 ----
    k_gemm_mfma<<<gemmGrid, 256, 0, stream>>>(bufA, W1t, dinv, Tb, N);
    k_aggb<<<aggbGrid, 256, 0, stream>>>(Tb, rowptr, csr_src, dinv, b1, bufA, N);
    // ---- GCN layer 3 ----
    k_gemm_mfma<<<gemmGrid, 256, 0, stream>>>(bufA, W2t, dinv, Tb, N);
    k_aggb<<<aggbGrid, 256, 0, stream>>>(Tb, rowptr, csr_src, dinv, b2, bufA, N);

    // ---- MLP head + pooled sums (256 nodes/block) ----
    k_mlp<<<(N + 255) / 256, 256, 0, stream>>>(bufA, Wf1t, bf1, Wf2t, bf2, Wf3, bf3,
                                               batch, util_sum, N, G);

    // ---- fused util + pairs ----
    int mx = (P > G ? P : G);
    k_out<<<(mx + 255) / 256, 256, 0, stream>>>(util_sum, cnt, idx_a, idx_b, out, P, G);
}